// Round 5
// baseline (336.015 us; speedup 1.0000x reference)
//
#include <hip/hip_runtime.h>
#include <hip/hip_bf16.h>
#include <math.h>

#define BB 8
#define NN 512
#define DD 512
#define NH 16
#define DH 32
#define NG 32
#define MAXD 128

typedef __attribute__((ext_vector_type(8))) short bf16x8;
typedef __attribute__((ext_vector_type(4))) float f32x4;

__device__ inline short f2bf(float x) {
    __hip_bfloat16 h = __float2bfloat16(x);
    return *reinterpret_cast<short*>(&h);
}
__device__ inline float bf2f(short x) {
    union { unsigned u; float f; } c;
    c.u = ((unsigned)(unsigned short)x) << 16;
    return c.f;
}

// async 16B global->LDS. lds dest must be WAVE-UNIFORM base; lane i lands at base + i*16.
__device__ inline void gld_lds16(const void* g, void* l) {
    __builtin_amdgcn_global_load_lds(
        (const __attribute__((address_space(1))) unsigned int*)g,
        (__attribute__((address_space(3))) unsigned int*)l, 16, 0, 0);
}

// ---------------- weight fp32 -> bf16 convert (4 arrays in one launch) ------
__global__ __launch_bounds__(256) void cvt_weights(
    const float* __restrict__ s0, const float* __restrict__ s1,
    const float* __restrict__ s2, const float* __restrict__ s3,
    short* __restrict__ d0, short* __restrict__ d1,
    short* __restrict__ d2, short* __restrict__ d3,
    int n0, int n1, int n2, int n3) {
    const float* s; short* d; int n;
    switch (blockIdx.y) {
        case 0: s = s0; d = d0; n = n0; break;
        case 1: s = s1; d = d1; n = n1; break;
        case 2: s = s2; d = d2; n = n2; break;
        default: s = s3; d = d3; n = n3; break;
    }
    const int i = (blockIdx.x * 256 + threadIdx.x) * 4;
    if (i >= n) return;
    const float4 v = *(const float4*)(s + i);
    short4 o;
    o.x = f2bf(v.x); o.y = f2bf(v.y); o.z = f2bf(v.z); o.w = f2bf(v.w);
    *(short4*)(d + i) = o;
}

// ---------------- LayerNorm: bf16 out (+ optional fp32 copy for residual) ---
__global__ __launch_bounds__(256) void ln_kernel(const float* __restrict__ x,
                                                 const float* __restrict__ g,
                                                 const float* __restrict__ b,
                                                 short* __restrict__ out_bf,
                                                 float* __restrict__ out_f) {
    const int row = blockIdx.x;
    const int tid = threadIdx.x;
    const float* xr = x + (size_t)row * DD;
    float v0 = xr[tid], v1 = xr[tid + 256];
    __shared__ float s1[256], s2[256];
    s1[tid] = v0 + v1;
    s2[tid] = v0 * v0 + v1 * v1;
    __syncthreads();
    for (int off = 128; off > 0; off >>= 1) {
        if (tid < off) { s1[tid] += s1[tid + off]; s2[tid] += s2[tid + off]; }
        __syncthreads();
    }
    const float mean = s1[0] * (1.0f / DD);
    const float var  = s2[0] * (1.0f / DD) - mean * mean;
    const float rs   = rsqrtf(var + 1e-5f);
    const float o0 = (v0 - mean) * rs * g[tid] + b[tid];
    const float o1 = (v1 - mean) * rs * g[tid + 256] + b[tid + 256];
    out_bf[(size_t)row * DD + tid]       = f2bf(o0);
    out_bf[(size_t)row * DD + tid + 256] = f2bf(o1);
    if (out_f) {
        out_f[(size_t)row * DD + tid]       = o0;
        out_f[(size_t)row * DD + tid + 256] = o1;
    }
}

// ---------------- bf16 MFMA GEMM: C = A @ W^T + bias (+gelu)(+res) ----------
// TM: row-tile (128 or 64), col-tile fixed 128. OUT: 0=f32, 1=bf16,
// 2=qkv-special (cols<1024 -> qk bf16 [M][1024]; cols>=1024 -> V transposed
// vt[(b*512 + (col-1024))][n] as short4-packed stores).
template <int TM, bool GELU, bool RES, int OUT>
__global__ __launch_bounds__(256) void gemm_bf16(
    const short* __restrict__ A, const short* __restrict__ Bw,
    const float* __restrict__ bias, const float* __restrict__ res,
    void* __restrict__ Cout, short* __restrict__ vt,
    int M, int Nout, int K) {
    const int MI = TM / 32;
    const int bm = blockIdx.y * TM;
    const int bn = blockIdx.x * 128;
    const int tid  = threadIdx.x;
    const int wave = tid >> 6;
    const int lane = tid & 63;
    const int l16  = lane & 15;
    const int quad = lane >> 4;
    const int wr = (wave >> 1) * (TM / 2);
    const int wc = (wave & 1) * 64;

    __shared__ short As[TM * 32];
    __shared__ short Bs[128 * 32];

    f32x4 acc[MI][4];
#pragma unroll
    for (int i = 0; i < MI; i++)
#pragma unroll
        for (int j = 0; j < 4; j++) acc[i][j] = (f32x4){0.f, 0.f, 0.f, 0.f};

    for (int k0 = 0; k0 < K; k0 += 32) {
        const short* Ab = A + (size_t)bm * K + k0;
        const short* Bb = Bw + (size_t)bn * K + k0;
#pragma unroll
        for (int j = 0; j < TM / 64; j++) {
            const int idx = j * 256 + wave * 64 + lane;
            gld_lds16(Ab + (size_t)(idx >> 2) * K + (idx & 3) * 8,
                      (short*)As + (size_t)(j * 256 + wave * 64) * 8);
        }
#pragma unroll
        for (int j = 0; j < 2; j++) {
            const int idx = j * 256 + wave * 64 + lane;
            gld_lds16(Bb + (size_t)(idx >> 2) * K + (idx & 3) * 8,
                      (short*)Bs + (size_t)(j * 256 + wave * 64) * 8);
        }
        __syncthreads();
        bf16x8 af[MI], bfr[4];
#pragma unroll
        for (int i = 0; i < MI; i++)
            af[i] = *(const bf16x8*)&As[(wr + i * 16 + l16) * 32 + quad * 8];
#pragma unroll
        for (int j = 0; j < 4; j++)
            bfr[j] = *(const bf16x8*)&Bs[(wc + j * 16 + l16) * 32 + quad * 8];
#pragma unroll
        for (int i = 0; i < MI; i++)
#pragma unroll
            for (int j = 0; j < 4; j++)
                acc[i][j] = __builtin_amdgcn_mfma_f32_16x16x32_bf16(af[i], bfr[j], acc[i][j], 0, 0, 0);
        __syncthreads();
    }
#pragma unroll
    for (int i = 0; i < MI; i++) {
#pragma unroll
        for (int j = 0; j < 4; j++) {
            const int col = bn + wc + j * 16 + l16;
            if (OUT == 2 && col >= 1024) {
                // V: pack 4 consecutive tokens into one short4 store
                const int n0 = bm + wr + i * 16 + quad * 4;
                const int cv = col - 1024;
                const float bv = bias[col];
                short4 o;
                o.x = f2bf(acc[i][j][0] + bv);
                o.y = f2bf(acc[i][j][1] + bv);
                o.z = f2bf(acc[i][j][2] + bv);
                o.w = f2bf(acc[i][j][3] + bv);
                *(short4*)&vt[((size_t)(n0 >> 9) * 512 + cv) * 512 + (n0 & 511)] = o;
            } else {
#pragma unroll
                for (int r = 0; r < 4; r++) {
                    const int row = bm + wr + i * 16 + quad * 4 + r;
                    float v = acc[i][j][r] + bias[col];
                    if (GELU) v = 0.5f * v * (1.0f + erff(v * 0.70710678118654752f));
                    if (RES)  v += res[(size_t)row * Nout + col];
                    if (OUT == 2)      ((short*)Cout)[(size_t)row * 1024 + col] = f2bf(v);
                    else if (OUT == 1) ((short*)Cout)[(size_t)row * Nout + col] = f2bf(v);
                    else               ((float*)Cout)[(size_t)row * Nout + col] = v;
                }
            }
        }
    }
}

// ---------------- MFMA flash attention, split-K, no-max softmax ----------
// 512 blocks: b = blk&7 (XCD-local), half = (blk>>3)&1, qtile = blk>>4.
// Q,K from qk [4096][1024]; V from vt [b][h*32+d][n] (transposed).
__global__ __launch_bounds__(512, 6) void attn_mfma(
    const short* __restrict__ qk,      // [4096][1024] bf16 (Q | K)
    const short* __restrict__ vt,      // [8][512][512] bf16 V^T per batch
    const int* __restrict__ dist,      // [B][N][N]
    const float* __restrict__ dist3d,  // [B][N][N]
    const float* __restrict__ demb,    // [128][16]
    const float* __restrict__ rbfw,    // [16][32]
    const float* __restrict__ rbfb,    // [16]
    float* __restrict__ O_part,        // [2][4096][512] fp32
    float* __restrict__ l_part)        // [2][4096][16]  fp32
{
    const int blk  = blockIdx.x;
    const int b    = blk & 7;
    const int half = (blk >> 3) & 1;
    const int q0   = (blk >> 4) * 16;
    const int tid  = threadIdx.x;
    const int wave = tid >> 6;
    const int lane = tid & 63;
    const int l16  = lane & 15;
    const int quad = lane >> 4;

    __shared__ short Kc[NH * 16 * 32];    // [h][k16][d32] bf16, 16 KB
    __shared__ short Vt[NH * 32 * 16];    // [h][d32][k16] bf16, 16 KB
    __shared__ short biasB[16 * 16 * 24]; // [q][k][h pad24] bf16, 12 KB
    __shared__ short Pb[8 * 16 * 32];     // per-wave [q16][k32] bf16, 8 KB

    for (int i = tid; i < 8 * 16 * 32; i += 512) Pb[i] = 0;

    const float scale = 0.17677669529663687f;  // 1/sqrt(32)
    bf16x8 qf[2];
#pragma unroll
    for (int h = 0; h < 2; h++) {
        const int hh = wave * 2 + h;
        qf[h] = *(const bf16x8*)(qk + (size_t)(b * NN + q0 + l16) * 1024 + hh * DH + quad * 8);
    }
    bf16x8 wf;
#pragma unroll
    for (int j = 0; j < 8; j++) wf[j] = f2bf(rbfw[l16 * NG + quad * 8 + j]);

    f32x4 O[2][2];
    float lsum[2][4];
#pragma unroll
    for (int h = 0; h < 2; h++) {
#pragma unroll
        for (int t = 0; t < 2; t++) O[h][t] = (f32x4){0.f, 0.f, 0.f, 0.f};
#pragma unroll
        for (int r = 0; r < 4; r++) lsum[h][r] = 0.f;
    }

    const float STEP  = 20.0f / 31.0f;
    const float COEFF = -0.5f / (STEP * STEP);

    for (int c = 0; c < 16; c++) {
        const int k0 = half * 256 + c * 16;
        __syncthreads();
        // ---- async stage: K (1024 chunks) + V^T (1024 chunks), 16B each ----
#pragma unroll
        for (int l = 0; l < 4; l++) {
            const int idxb = l * 512 + wave * 64;
            const int idx  = idxb + lane;
            if (l < 2) {
                const int h = idx >> 6, k = (idx >> 2) & 15, c4 = idx & 3;
                const short* src = qk + (size_t)(b * NN + k0 + k) * 1024 + 512 + h * DH + c4 * 8;
                gld_lds16(src, (short*)Kc + (size_t)idxb * 8);
            } else {
                const int vi = idx - 1024;
                const int hd = vi >> 1, c2 = vi & 1;
                const short* src = vt + ((size_t)b * 512 + hd) * 512 + k0 + c2 * 8;
                gld_lds16(src, (short*)Vt + (size_t)(idxb - 1024) * 8);
            }
        }
        // ---- bias MFMA: wave handles q-rows wave*2, wave*2+1 ----
#pragma unroll
        for (int g = 0; g < 2; g++) {
            const int qloc = wave * 2 + g;
            const size_t rowbase = ((size_t)(b * NN) + q0 + qloc) * NN + k0;
            const float d3 = dist3d[rowbase + l16];
            bf16x8 ef;
#pragma unroll
            for (int j = 0; j < 8; j++) {
                const float t = d3 - (float)(quad * 8 + j) * STEP;
                ef[j] = f2bf(__expf(COEFF * t * t));
            }
            f32x4 cc;
            const float rb = rbfb[l16];
#pragma unroll
            for (int r = 0; r < 4; r++) {
                int dc = dist[rowbase + quad * 4 + r];
                dc = min(max(dc, 0), MAXD - 1);
                cc[r] = demb[dc * NH + l16] + rb;
            }
            const f32x4 dres = __builtin_amdgcn_mfma_f32_16x16x32_bf16(ef, wf, cc, 0, 0, 0);
#pragma unroll
            for (int r = 0; r < 4; r++)
                biasB[(qloc * 16 + quad * 4 + r) * 24 + l16] = f2bf(dres[r]);
        }
        __syncthreads();
        // ---- per-head: QK^T MFMA, bias, exp (no max shift), PV MFMA ----
#pragma unroll
        for (int h = 0; h < 2; h++) {
            const int hh = wave * 2 + h;
            const bf16x8 kf = *(const bf16x8*)&Kc[(hh * 16 + l16) * 32 + quad * 8];
            f32x4 s = __builtin_amdgcn_mfma_f32_16x16x32_bf16(
                qf[h], kf, (f32x4){0.f, 0.f, 0.f, 0.f}, 0, 0, 0);
            float pv[4];
#pragma unroll
            for (int r = 0; r < 4; r++) {
                float sv = s[r] * scale + bf2f(biasB[((quad * 4 + r) * 16 + l16) * 24 + hh]);
                sv = fminf(sv, 20.f);
                pv[r] = __expf(sv);
                lsum[h][r] += pv[r];
                Pb[wave * 512 + (quad * 4 + r) * 32 + l16] = f2bf(pv[r]);
            }
            const bf16x8 pf = *(const bf16x8*)&Pb[wave * 512 + l16 * 32 + quad * 8];
#pragma unroll
            for (int t = 0; t < 2; t++) {
                bf16x8 vf;
                if (quad < 2) {
                    vf = *(const bf16x8*)&Vt[(hh * 32 + t * 16 + l16) * 16 + quad * 8];
                } else {
#pragma unroll
                    for (int j = 0; j < 8; j++) vf[j] = 0;
                }
                O[h][t] = __builtin_amdgcn_mfma_f32_16x16x32_bf16(pf, vf, O[h][t], 0, 0, 0);
            }
        }
    }
    // ---- epilogue ----
    const size_t halfoff = (size_t)half * 4096;
#pragma unroll
    for (int h = 0; h < 2; h++) {
        const int hh = wave * 2 + h;
#pragma unroll
        for (int m = 1; m < 16; m <<= 1)
#pragma unroll
            for (int r = 0; r < 4; r++) lsum[h][r] += __shfl_xor(lsum[h][r], m);
#pragma unroll
        for (int r = 0; r < 4; r++) {
            const size_t row = (size_t)(b * NN + q0 + quad * 4 + r);
#pragma unroll
            for (int t = 0; t < 2; t++)
                O_part[(halfoff + row) * DD + hh * DH + t * 16 + l16] = O[h][t][r];
            if (l16 == 0) l_part[(halfoff + row) * NH + hh] = lsum[h][r];
        }
    }
}

// ---------------- combine split-K partials -> ctx bf16 ----------------
__global__ __launch_bounds__(256) void attn_combine(
    const float* __restrict__ O_part, const float* __restrict__ l_part,
    short* __restrict__ ctx) {
    const int e = (blockIdx.x * 256 + threadIdx.x) * 4;
    const int row = e >> 9, d = e & 511, h = d >> 5;
    const float4 o0 = *(const float4*)(O_part + e);
    const float4 o1 = *(const float4*)(O_part + (size_t)4096 * 512 + e);
    const float l = l_part[row * NH + h] + l_part[4096 * NH + row * NH + h];
    const float rinv = 1.0f / l;
    short4 o;
    o.x = f2bf((o0.x + o1.x) * rinv);
    o.y = f2bf((o0.y + o1.y) * rinv);
    o.z = f2bf((o0.z + o1.z) * rinv);
    o.w = f2bf((o0.w + o1.w) * rinv);
    *(short4*)(ctx + e) = o;
}

extern "C" void kernel_launch(void* const* d_in, const int* in_sizes, int n_in,
                              void* d_out, int out_size, void* d_ws, size_t ws_size,
                              hipStream_t stream) {
    const float* x      = (const float*)d_in[0];
    const int*   dist   = (const int*)d_in[1];
    const float* dist3d = (const float*)d_in[2];
    const float* n1g    = (const float*)d_in[3];
    const float* n1b    = (const float*)d_in[4];
    const float* win    = (const float*)d_in[5];
    const float* bin    = (const float*)d_in[6];
    const float* wo     = (const float*)d_in[7];
    const float* bo     = (const float*)d_in[8];
    const float* demb   = (const float*)d_in[9];
    const float* rbfw   = (const float*)d_in[10];
    const float* rbfb   = (const float*)d_in[11];
    const float* n2g    = (const float*)d_in[12];
    const float* n2b    = (const float*)d_in[13];
    const float* w1     = (const float*)d_in[14];
    const float* b1     = (const float*)d_in[15];
    const float* w2     = (const float*)d_in[16];
    const float* b2     = (const float*)d_in[17];

    char* p = (char*)d_ws;
    short* h_bf   = (short*)p; p += (size_t)4096 * 512 * 2;
    float* h_f    = (float*)p; p += (size_t)4096 * 512 * 4;
    short* qk_bf  = (short*)p; p += (size_t)4096 * 1024 * 2;
    short* vt_bf  = (short*)p; p += (size_t)4096 * 512 * 2;
    short* ctx_bf = (short*)p; p += (size_t)4096 * 512 * 2;
    float* hres   = (float*)p; p += (size_t)4096 * 512 * 4;
    short* h2_bf  = (short*)p; p += (size_t)4096 * 512 * 2;
    short* mid_bf = (short*)p; p += (size_t)4096 * 2048 * 2;
    short* win_bf = (short*)p; p += (size_t)1536 * 512 * 2;
    short* wo_bf  = (short*)p; p += (size_t)512 * 512 * 2;
    short* w1_bf  = (short*)p; p += (size_t)2048 * 512 * 2;
    short* w2_bf  = (short*)p; p += (size_t)512 * 2048 * 2;
    float* O_part = (float*)p; p += (size_t)2 * 4096 * 512 * 4;
    float* l_part = (float*)p; p += (size_t)2 * 4096 * 16 * 4;

    const int M = BB * NN;  // 4096

    cvt_weights<<<dim3(1024, 4), 256, 0, stream>>>(
        win, wo, w1, w2, win_bf, wo_bf, w1_bf, w2_bf,
        1536 * 512, 512 * 512, 2048 * 512, 512 * 2048);
    ln_kernel<<<M, 256, 0, stream>>>(x, n1g, n1b, h_bf, h_f);
    gemm_bf16<128, false, false, 2><<<dim3(12, 32), 256, 0, stream>>>(
        h_bf, win_bf, bin, nullptr, qk_bf, vt_bf, M, 1536, DD);
    attn_mfma<<<512, 512, 0, stream>>>(
        qk_bf, vt_bf, dist, dist3d, demb, rbfw, rbfb, O_part, l_part);
    attn_combine<<<2048, 256, 0, stream>>>(O_part, l_part, ctx_bf);
    gemm_bf16<64, false, true, 0><<<dim3(4, 64), 256, 0, stream>>>(
        ctx_bf, wo_bf, bo, h_f, hres, nullptr, M, DD, DD);
    ln_kernel<<<M, 256, 0, stream>>>(hres, n2g, n2b, h2_bf, nullptr);
    gemm_bf16<128, true, false, 1><<<dim3(16, 32), 256, 0, stream>>>(
        h2_bf, w1_bf, b1, nullptr, mid_bf, nullptr, M, 2048, DD);
    gemm_bf16<64, false, true, 0><<<dim3(4, 64), 256, 0, stream>>>(
        mid_bf, w2_bf, b2, hres, (float*)d_out, nullptr, M, DD, 2048);
}

// Round 6
// 277.289 us; speedup vs baseline: 1.2118x; 1.2118x over previous
//
#include <hip/hip_runtime.h>
#include <hip/hip_bf16.h>
#include <math.h>

#define BB 8
#define NN 512
#define DD 512
#define NH 16
#define DH 32
#define TD 1536
#define NG 32
#define MAXD 128

typedef __attribute__((ext_vector_type(8))) short bf16x8;
typedef __attribute__((ext_vector_type(4))) float f32x4;

__device__ inline short f2bf(float x) {
    __hip_bfloat16 h = __float2bfloat16(x);
    return *reinterpret_cast<short*>(&h);
}
__device__ inline float bf2f(short x) {
    union { unsigned u; float f; } c;
    c.u = ((unsigned)(unsigned short)x) << 16;
    return c.f;
}

// async 16B global->LDS. lds dest must be WAVE-UNIFORM base; lane i lands at base + i*16.
__device__ inline void gld_lds16(const void* g, void* l) {
    __builtin_amdgcn_global_load_lds(
        (const __attribute__((address_space(1))) unsigned int*)g,
        (__attribute__((address_space(3))) unsigned int*)l, 16, 0, 0);
}

// ---------------- weight fp32 -> bf16 convert (4 arrays in one launch) ------
__global__ __launch_bounds__(256) void cvt_weights(
    const float* __restrict__ s0, const float* __restrict__ s1,
    const float* __restrict__ s2, const float* __restrict__ s3,
    short* __restrict__ d0, short* __restrict__ d1,
    short* __restrict__ d2, short* __restrict__ d3,
    int n0, int n1, int n2, int n3) {
    const float* s; short* d; int n;
    switch (blockIdx.y) {
        case 0: s = s0; d = d0; n = n0; break;
        case 1: s = s1; d = d1; n = n1; break;
        case 2: s = s2; d = d2; n = n2; break;
        default: s = s3; d = d3; n = n3; break;
    }
    const int i = (blockIdx.x * 256 + threadIdx.x) * 4;
    if (i >= n) return;
    const float4 v = *(const float4*)(s + i);
    short4 o;
    o.x = f2bf(v.x); o.y = f2bf(v.y); o.z = f2bf(v.z); o.w = f2bf(v.w);
    *(short4*)(d + i) = o;
}

// ---------------- LayerNorm: bf16 out (+ optional fp32 copy for residual) ---
__global__ __launch_bounds__(256) void ln_kernel(const float* __restrict__ x,
                                                 const float* __restrict__ g,
                                                 const float* __restrict__ b,
                                                 short* __restrict__ out_bf,
                                                 float* __restrict__ out_f) {
    const int row = blockIdx.x;
    const int tid = threadIdx.x;
    const float* xr = x + (size_t)row * DD;
    float v0 = xr[tid], v1 = xr[tid + 256];
    __shared__ float s1[256], s2[256];
    s1[tid] = v0 + v1;
    s2[tid] = v0 * v0 + v1 * v1;
    __syncthreads();
    for (int off = 128; off > 0; off >>= 1) {
        if (tid < off) { s1[tid] += s1[tid + off]; s2[tid] += s2[tid + off]; }
        __syncthreads();
    }
    const float mean = s1[0] * (1.0f / DD);
    const float var  = s2[0] * (1.0f / DD) - mean * mean;
    const float rs   = rsqrtf(var + 1e-5f);
    const float o0 = (v0 - mean) * rs * g[tid] + b[tid];
    const float o1 = (v1 - mean) * rs * g[tid + 256] + b[tid + 256];
    out_bf[(size_t)row * DD + tid]       = f2bf(o0);
    out_bf[(size_t)row * DD + tid + 256] = f2bf(o1);
    if (out_f) {
        out_f[(size_t)row * DD + tid]       = o0;
        out_f[(size_t)row * DD + tid + 256] = o1;
    }
}

// ---------------- bf16 MFMA GEMM: C = A @ W^T + bias (+gelu)(+res) ----------
// TM: row-tile (128 or 64), col-tile fixed 128. OUT: 0=f32, 1=bf16.
template <int TM, bool GELU, bool RES, int OUT>
__global__ __launch_bounds__(256) void gemm_bf16(
    const short* __restrict__ A, const short* __restrict__ Bw,
    const float* __restrict__ bias, const float* __restrict__ res,
    void* __restrict__ Cout, int M, int Nout, int K) {
    const int MI = TM / 32;
    const int bm = blockIdx.y * TM;
    const int bn = blockIdx.x * 128;
    const int tid  = threadIdx.x;
    const int wave = tid >> 6;
    const int lane = tid & 63;
    const int l16  = lane & 15;
    const int quad = lane >> 4;
    const int wr = (wave >> 1) * (TM / 2);
    const int wc = (wave & 1) * 64;

    __shared__ short As[TM * 32];
    __shared__ short Bs[128 * 32];

    f32x4 acc[MI][4];
#pragma unroll
    for (int i = 0; i < MI; i++)
#pragma unroll
        for (int j = 0; j < 4; j++) acc[i][j] = (f32x4){0.f, 0.f, 0.f, 0.f};

    for (int k0 = 0; k0 < K; k0 += 32) {
        const short* Ab = A + (size_t)bm * K + k0;
        const short* Bb = Bw + (size_t)bn * K + k0;
#pragma unroll
        for (int j = 0; j < TM / 64; j++) {
            const int idx = j * 256 + wave * 64 + lane;
            gld_lds16(Ab + (size_t)(idx >> 2) * K + (idx & 3) * 8,
                      (short*)As + (size_t)(j * 256 + wave * 64) * 8);
        }
#pragma unroll
        for (int j = 0; j < 2; j++) {
            const int idx = j * 256 + wave * 64 + lane;
            gld_lds16(Bb + (size_t)(idx >> 2) * K + (idx & 3) * 8,
                      (short*)Bs + (size_t)(j * 256 + wave * 64) * 8);
        }
        __syncthreads();
        bf16x8 af[MI], bfr[4];
#pragma unroll
        for (int i = 0; i < MI; i++)
            af[i] = *(const bf16x8*)&As[(wr + i * 16 + l16) * 32 + quad * 8];
#pragma unroll
        for (int j = 0; j < 4; j++)
            bfr[j] = *(const bf16x8*)&Bs[(wc + j * 16 + l16) * 32 + quad * 8];
#pragma unroll
        for (int i = 0; i < MI; i++)
#pragma unroll
            for (int j = 0; j < 4; j++)
                acc[i][j] = __builtin_amdgcn_mfma_f32_16x16x32_bf16(af[i], bfr[j], acc[i][j], 0, 0, 0);
        __syncthreads();
    }
#pragma unroll
    for (int i = 0; i < MI; i++) {
#pragma unroll
        for (int r = 0; r < 4; r++) {
            const int row = bm + wr + i * 16 + quad * 4 + r;
#pragma unroll
            for (int j = 0; j < 4; j++) {
                const int col = bn + wc + j * 16 + l16;
                float v = acc[i][j][r] + bias[col];
                if (GELU) v = 0.5f * v * (1.0f + erff(v * 0.70710678118654752f));
                if (RES)  v += res[(size_t)row * Nout + col];
                if (OUT == 1) ((short*)Cout)[(size_t)row * Nout + col] = f2bf(v);
                else          ((float*)Cout)[(size_t)row * Nout + col] = v;
            }
        }
    }
}

// ---------------- MFMA flash attention, 4-way split-K, no-max softmax -------
// 1024 blocks: b = blk&7 (XCD-local), part = (blk>>3)&3, qtile = blk>>5.
// Each block: 16 q-rows x 128 keys (8 chunks of 16). Outputs unnormalized
// partial O (fp32) + partial row-sums l; combine kernel normalizes.
__global__ __launch_bounds__(512) void attn_mfma(
    const short* __restrict__ qkv,     // [4096][1536] bf16
    const int* __restrict__ dist,      // [B][N][N]
    const float* __restrict__ dist3d,  // [B][N][N]
    const float* __restrict__ demb,    // [128][16]
    const float* __restrict__ rbfw,    // [16][32]
    const float* __restrict__ rbfb,    // [16]
    float* __restrict__ O_part,        // [4][4096][512] fp32
    float* __restrict__ l_part)        // [4][4096][16]  fp32
{
    const int blk  = blockIdx.x;
    const int b    = blk & 7;
    const int part = (blk >> 3) & 3;
    const int q0   = (blk >> 5) * 16;
    const int tid  = threadIdx.x;
    const int wave = tid >> 6;
    const int lane = tid & 63;
    const int l16  = lane & 15;
    const int quad = lane >> 4;

    __shared__ short Kc[NH * 16 * 32];    // [h][k16][d32] bf16, 16 KB
    __shared__ short Vc[NH * 16 * 32];    // [h][k16][d32] bf16, 16 KB
    __shared__ short biasB[16 * 16 * 24]; // [q][k][h pad24] bf16, 12 KB
    __shared__ short Pb[8 * 16 * 32];     // per-wave [q16][k32] bf16, 8 KB

    for (int i = tid; i < 8 * 16 * 32; i += 512) Pb[i] = 0;

    const float scale = 0.17677669529663687f;  // 1/sqrt(32)
    bf16x8 qf[2];
#pragma unroll
    for (int h = 0; h < 2; h++) {
        const int hh = wave * 2 + h;
        qf[h] = *(const bf16x8*)(qkv + (size_t)(b * NN + q0 + l16) * TD + hh * DH + quad * 8);
    }
    bf16x8 wf;
#pragma unroll
    for (int j = 0; j < 8; j++) wf[j] = f2bf(rbfw[l16 * NG + quad * 8 + j]);

    f32x4 O[2][2];
    float lsum[2][4];
#pragma unroll
    for (int h = 0; h < 2; h++) {
#pragma unroll
        for (int t = 0; t < 2; t++) O[h][t] = (f32x4){0.f, 0.f, 0.f, 0.f};
#pragma unroll
        for (int r = 0; r < 4; r++) lsum[h][r] = 0.f;
    }

    const float STEP  = 20.0f / 31.0f;
    const float COEFF = -0.5f / (STEP * STEP);

    for (int c = 0; c < 8; c++) {
        const int k0 = part * 128 + c * 16;
        __syncthreads();
        // ---- async stage K,V chunk (2048 x 16B chunks) ----
#pragma unroll
        for (int l = 0; l < 4; l++) {
            const int idxb = l * 512 + wave * 64;
            const int idx  = idxb + lane;
            const int kk2  = idx & 1023;
            const int h = kk2 >> 6, k = (kk2 >> 2) & 15, c4 = kk2 & 3;
            const short* src = qkv + (size_t)(b * NN + k0 + k) * TD +
                               DD * (1 + (l >> 1)) + h * 32 + c4 * 8;
            short* dstb = (l < 2 ? (short*)Kc : (short*)Vc) + (size_t)(idxb & 1023) * 8;
            gld_lds16(src, dstb);
        }
        // ---- bias MFMA: wave handles q-rows wave*2, wave*2+1 ----
#pragma unroll
        for (int g = 0; g < 2; g++) {
            const int qloc = wave * 2 + g;
            const size_t rowbase = ((size_t)(b * NN) + q0 + qloc) * NN + k0;
            const float d3 = dist3d[rowbase + l16];
            bf16x8 ef;
#pragma unroll
            for (int j = 0; j < 8; j++) {
                const float t = d3 - (float)(quad * 8 + j) * STEP;
                ef[j] = f2bf(__expf(COEFF * t * t));
            }
            f32x4 cc;
            const float rb = rbfb[l16];
#pragma unroll
            for (int r = 0; r < 4; r++) {
                int dc = dist[rowbase + quad * 4 + r];
                dc = min(max(dc, 0), MAXD - 1);
                cc[r] = demb[dc * NH + l16] + rb;
            }
            const f32x4 dres = __builtin_amdgcn_mfma_f32_16x16x32_bf16(ef, wf, cc, 0, 0, 0);
#pragma unroll
            for (int r = 0; r < 4; r++)
                biasB[(qloc * 16 + quad * 4 + r) * 24 + l16] = f2bf(dres[r]);
        }
        __syncthreads();
        // ---- per-head: QK^T MFMA, bias, exp (no max shift), PV MFMA ----
#pragma unroll
        for (int h = 0; h < 2; h++) {
            const int hh = wave * 2 + h;
            const bf16x8 kf = *(const bf16x8*)&Kc[hh * 512 + l16 * 32 + quad * 8];
            f32x4 s = __builtin_amdgcn_mfma_f32_16x16x32_bf16(
                qf[h], kf, (f32x4){0.f, 0.f, 0.f, 0.f}, 0, 0, 0);
            float pv[4];
#pragma unroll
            for (int r = 0; r < 4; r++) {
                float sv = s[r] * scale + bf2f(biasB[((quad * 4 + r) * 16 + l16) * 24 + hh]);
                sv = fminf(sv, 20.f);
                pv[r] = __expf(sv);
                lsum[h][r] += pv[r];
                Pb[wave * 512 + (quad * 4 + r) * 32 + l16] = f2bf(pv[r]);
            }
            const bf16x8 pf = *(const bf16x8*)&Pb[wave * 512 + l16 * 32 + quad * 8];
#pragma unroll
            for (int t = 0; t < 2; t++) {
                bf16x8 vf;
                if (quad < 2) {
#pragma unroll
                    for (int j = 0; j < 8; j++)
                        vf[j] = Vc[hh * 512 + (quad * 8 + j) * 32 + t * 16 + l16];
                } else {
#pragma unroll
                    for (int j = 0; j < 8; j++) vf[j] = 0;
                }
                O[h][t] = __builtin_amdgcn_mfma_f32_16x16x32_bf16(pf, vf, O[h][t], 0, 0, 0);
            }
        }
    }
    // ---- epilogue: reduce lsum across the 16-lane k groups, write partials --
    const size_t poff = (size_t)part * 4096;
#pragma unroll
    for (int h = 0; h < 2; h++) {
        const int hh = wave * 2 + h;
#pragma unroll
        for (int m = 1; m < 16; m <<= 1)
#pragma unroll
            for (int r = 0; r < 4; r++) lsum[h][r] += __shfl_xor(lsum[h][r], m);
#pragma unroll
        for (int r = 0; r < 4; r++) {
            const size_t row = (size_t)(b * NN + q0 + quad * 4 + r);
#pragma unroll
            for (int t = 0; t < 2; t++)
                O_part[(poff + row) * DD + hh * DH + t * 16 + l16] = O[h][t][r];
            if (l16 == 0) l_part[(poff + row) * NH + hh] = lsum[h][r];
        }
    }
}

// ---------------- combine split-K partials -> ctx bf16 ----------------
__global__ __launch_bounds__(256) void attn_combine(
    const float* __restrict__ O_part, const float* __restrict__ l_part,
    short* __restrict__ ctx) {
    const int e = (blockIdx.x * 256 + threadIdx.x) * 4;
    const int row = e >> 9, d = e & 511, h = d >> 5;
    const size_t PO = (size_t)4096 * 512;
    const float4 o0 = *(const float4*)(O_part + e);
    const float4 o1 = *(const float4*)(O_part + PO + e);
    const float4 o2 = *(const float4*)(O_part + 2 * PO + e);
    const float4 o3 = *(const float4*)(O_part + 3 * PO + e);
    const int li = row * NH + h;
    const float l = l_part[li] + l_part[4096 * NH + li] +
                    l_part[2 * 4096 * NH + li] + l_part[3 * 4096 * NH + li];
    const float rinv = 1.0f / l;
    short4 o;
    o.x = f2bf((o0.x + o1.x + o2.x + o3.x) * rinv);
    o.y = f2bf((o0.y + o1.y + o2.y + o3.y) * rinv);
    o.z = f2bf((o0.z + o1.z + o2.z + o3.z) * rinv);
    o.w = f2bf((o0.w + o1.w + o2.w + o3.w) * rinv);
    *(short4*)(ctx + e) = o;
}

extern "C" void kernel_launch(void* const* d_in, const int* in_sizes, int n_in,
                              void* d_out, int out_size, void* d_ws, size_t ws_size,
                              hipStream_t stream) {
    const float* x      = (const float*)d_in[0];
    const int*   dist   = (const int*)d_in[1];
    const float* dist3d = (const float*)d_in[2];
    const float* n1g    = (const float*)d_in[3];
    const float* n1b    = (const float*)d_in[4];
    const float* win    = (const float*)d_in[5];
    const float* bin    = (const float*)d_in[6];
    const float* wo     = (const float*)d_in[7];
    const float* bo     = (const float*)d_in[8];
    const float* demb   = (const float*)d_in[9];
    const float* rbfw   = (const float*)d_in[10];
    const float* rbfb   = (const float*)d_in[11];
    const float* n2g    = (const float*)d_in[12];
    const float* n2b    = (const float*)d_in[13];
    const float* w1     = (const float*)d_in[14];
    const float* b1     = (const float*)d_in[15];
    const float* w2     = (const float*)d_in[16];
    const float* b2     = (const float*)d_in[17];

    char* p = (char*)d_ws;
    short* h_bf   = (short*)p; p += (size_t)4096 * 512 * 2;   // 4 MB
    float* h_f    = (float*)p; p += (size_t)4096 * 512 * 4;   // 8 MB
    short* qkv_bf = (short*)p; p += (size_t)4096 * 1536 * 2;  // 12 MB
    short* ctx_bf = (short*)p; p += (size_t)4096 * 512 * 2;   // 4 MB
    float* hres   = (float*)p; p += (size_t)4096 * 512 * 4;   // 8 MB
    short* h2_bf  = (short*)p; p += (size_t)4096 * 512 * 2;   // 4 MB
    short* win_bf = (short*)p; p += (size_t)1536 * 512 * 2;
    short* wo_bf  = (short*)p; p += (size_t)512 * 512 * 2;
    short* w1_bf  = (short*)p; p += (size_t)2048 * 512 * 2;
    short* w2_bf  = (short*)p; p += (size_t)512 * 2048 * 2;   // weights 6 MB
    float* O_part = (float*)p;                                 // 32 MB
    short* mid_bf = (short*)p;  // overlays O_part (dead after combine)
    p += (size_t)4 * 4096 * 512 * 4;
    float* l_part = (float*)p; p += (size_t)4 * 4096 * 16 * 4; // 1 MB

    const int M = BB * NN;  // 4096

    cvt_weights<<<dim3(1024, 4), 256, 0, stream>>>(
        win, wo, w1, w2, win_bf, wo_bf, w1_bf, w2_bf,
        1536 * 512, 512 * 512, 2048 * 512, 512 * 2048);
    ln_kernel<<<M, 256, 0, stream>>>(x, n1g, n1b, h_bf, h_f);
    gemm_bf16<128, false, false, 1><<<dim3(12, 32), 256, 0, stream>>>(
        h_bf, win_bf, bin, nullptr, qkv_bf, M, TD, DD);
    attn_mfma<<<1024, 512, 0, stream>>>(
        qkv_bf, dist, dist3d, demb, rbfw, rbfb, O_part, l_part);
    attn_combine<<<2048, 256, 0, stream>>>(O_part, l_part, ctx_bf);
    gemm_bf16<64, false, true, 0><<<dim3(4, 64), 256, 0, stream>>>(
        ctx_bf, wo_bf, bo, h_f, hres, M, DD, DD);
    ln_kernel<<<M, 256, 0, stream>>>(hres, n2g, n2b, h2_bf, nullptr);
    gemm_bf16<128, true, false, 1><<<dim3(16, 32), 256, 0, stream>>>(
        h2_bf, w1_bf, b1, nullptr, mid_bf, M, 2048, DD);
    gemm_bf16<64, false, true, 0><<<dim3(4, 64), 256, 0, stream>>>(
        mid_bf, w2_bf, b2, hres, (float*)d_out, M, DD, 2048);
}

// Round 8
// 267.211 us; speedup vs baseline: 1.2575x; 1.0377x over previous
//
#include <hip/hip_runtime.h>
#include <hip/hip_bf16.h>
#include <math.h>

#define BB 8
#define NN 512
#define DD 512
#define NH 16
#define DH 32
#define TD 1536
#define NG 32
#define MAXD 128

typedef __attribute__((ext_vector_type(8))) short bf16x8;
typedef __attribute__((ext_vector_type(4))) float f32x4;

__device__ inline short f2bf(float x) {
    __hip_bfloat16 h = __float2bfloat16(x);
    return *reinterpret_cast<short*>(&h);
}
__device__ inline float bf2f(short x) {
    union { unsigned u; float f; } c;
    c.u = ((unsigned)(unsigned short)x) << 16;
    return c.f;
}

// async 16B global->LDS. lds dest must be WAVE-UNIFORM base; lane i lands at base + i*16.
__device__ inline void gld_lds16(const void* g, void* l) {
    __builtin_amdgcn_global_load_lds(
        (const __attribute__((address_space(1))) unsigned int*)g,
        (__attribute__((address_space(3))) unsigned int*)l, 16, 0, 0);
}

// ---------------- weight fp32 -> bf16 convert (4 arrays in one launch) ------
__global__ __launch_bounds__(256) void cvt_weights(
    const float* __restrict__ s0, const float* __restrict__ s1,
    const float* __restrict__ s2, const float* __restrict__ s3,
    short* __restrict__ d0, short* __restrict__ d1,
    short* __restrict__ d2, short* __restrict__ d3,
    int n0, int n1, int n2, int n3) {
    const float* s; short* d; int n;
    switch (blockIdx.y) {
        case 0: s = s0; d = d0; n = n0; break;
        case 1: s = s1; d = d1; n = n1; break;
        case 2: s = s2; d = d2; n = n2; break;
        default: s = s3; d = d3; n = n3; break;
    }
    const int i = (blockIdx.x * 256 + threadIdx.x) * 4;
    if (i >= n) return;
    const float4 v = *(const float4*)(s + i);
    short4 o;
    o.x = f2bf(v.x); o.y = f2bf(v.y); o.z = f2bf(v.z); o.w = f2bf(v.w);
    *(short4*)(d + i) = o;
}

// ---------------- RBF bias table: T[i][h] = rbf_b[h] + sum_g e_g(x_i) w[h][g]
// 129 nodes on [0,20] (+1 guard row). Linear interp error ~3e-4.
__global__ __launch_bounds__(256) void rbf_table(
    const float* __restrict__ rbfw, const float* __restrict__ rbfb,
    short* __restrict__ Tg) {
    const int idx = blockIdx.x * 256 + threadIdx.x;
    if (idx >= 130 * 16) return;
    const int i = idx >> 4, h = idx & 15;
    const float STEP  = 20.0f / 31.0f;
    const float COEFF = -0.5f / (STEP * STEP);
    const float x = fminf((float)i, 128.0f) * (20.0f / 128.0f);
    float acc = rbfb[h];
#pragma unroll
    for (int g = 0; g < NG; g++) {
        const float t = x - (float)g * STEP;
        acc += __expf(COEFF * t * t) * rbfw[h * NG + g];
    }
    Tg[idx] = f2bf(acc);
}

// ---------------- LayerNorm: bf16 out (+ optional fp32 copy for residual) ---
__global__ __launch_bounds__(256) void ln_kernel(const float* __restrict__ x,
                                                 const float* __restrict__ g,
                                                 const float* __restrict__ b,
                                                 short* __restrict__ out_bf,
                                                 float* __restrict__ out_f) {
    const int row = blockIdx.x;
    const int tid = threadIdx.x;
    const float* xr = x + (size_t)row * DD;
    float v0 = xr[tid], v1 = xr[tid + 256];
    __shared__ float s1[256], s2[256];
    s1[tid] = v0 + v1;
    s2[tid] = v0 * v0 + v1 * v1;
    __syncthreads();
    for (int off = 128; off > 0; off >>= 1) {
        if (tid < off) { s1[tid] += s1[tid + off]; s2[tid] += s2[tid + off]; }
        __syncthreads();
    }
    const float mean = s1[0] * (1.0f / DD);
    const float var  = s2[0] * (1.0f / DD) - mean * mean;
    const float rs   = rsqrtf(var + 1e-5f);
    const float o0 = (v0 - mean) * rs * g[tid] + b[tid];
    const float o1 = (v1 - mean) * rs * g[tid + 256] + b[tid + 256];
    out_bf[(size_t)row * DD + tid]       = f2bf(o0);
    out_bf[(size_t)row * DD + tid + 256] = f2bf(o1);
    if (out_f) {
        out_f[(size_t)row * DD + tid]       = o0;
        out_f[(size_t)row * DD + tid + 256] = o1;
    }
}

// ---------------- bf16 MFMA GEMM: C = A @ W^T + bias (+gelu)(+res) ----------
template <int TM, bool GELU, bool RES, int OUT>
__global__ __launch_bounds__(256) void gemm_bf16(
    const short* __restrict__ A, const short* __restrict__ Bw,
    const float* __restrict__ bias, const float* __restrict__ res,
    void* __restrict__ Cout, int M, int Nout, int K) {
    const int MI = TM / 32;
    const int bm = blockIdx.y * TM;
    const int bn = blockIdx.x * 128;
    const int tid  = threadIdx.x;
    const int wave = tid >> 6;
    const int lane = tid & 63;
    const int l16  = lane & 15;
    const int quad = lane >> 4;
    const int wr = (wave >> 1) * (TM / 2);
    const int wc = (wave & 1) * 64;

    __shared__ short As[TM * 32];
    __shared__ short Bs[128 * 32];

    f32x4 acc[MI][4];
#pragma unroll
    for (int i = 0; i < MI; i++)
#pragma unroll
        for (int j = 0; j < 4; j++) acc[i][j] = (f32x4){0.f, 0.f, 0.f, 0.f};

    for (int k0 = 0; k0 < K; k0 += 32) {
        const short* Ab = A + (size_t)bm * K + k0;
        const short* Bb = Bw + (size_t)bn * K + k0;
#pragma unroll
        for (int j = 0; j < TM / 64; j++) {
            const int idx = j * 256 + wave * 64 + lane;
            gld_lds16(Ab + (size_t)(idx >> 2) * K + (idx & 3) * 8,
                      (short*)As + (size_t)(j * 256 + wave * 64) * 8);
        }
#pragma unroll
        for (int j = 0; j < 2; j++) {
            const int idx = j * 256 + wave * 64 + lane;
            gld_lds16(Bb + (size_t)(idx >> 2) * K + (idx & 3) * 8,
                      (short*)Bs + (size_t)(j * 256 + wave * 64) * 8);
        }
        __syncthreads();
        bf16x8 af[MI], bfr[4];
#pragma unroll
        for (int i = 0; i < MI; i++)
            af[i] = *(const bf16x8*)&As[(wr + i * 16 + l16) * 32 + quad * 8];
#pragma unroll
        for (int j = 0; j < 4; j++)
            bfr[j] = *(const bf16x8*)&Bs[(wc + j * 16 + l16) * 32 + quad * 8];
#pragma unroll
        for (int i = 0; i < MI; i++)
#pragma unroll
            for (int j = 0; j < 4; j++)
                acc[i][j] = __builtin_amdgcn_mfma_f32_16x16x32_bf16(af[i], bfr[j], acc[i][j], 0, 0, 0);
        __syncthreads();
    }
#pragma unroll
    for (int i = 0; i < MI; i++) {
#pragma unroll
        for (int r = 0; r < 4; r++) {
            const int row = bm + wr + i * 16 + quad * 4 + r;
#pragma unroll
            for (int j = 0; j < 4; j++) {
                const int col = bn + wc + j * 16 + l16;
                float v = acc[i][j][r] + bias[col];
                if (GELU) v = 0.5f * v * (1.0f + erff(v * 0.70710678118654752f));
                if (RES)  v += res[(size_t)row * Nout + col];
                if (OUT == 1) ((short*)Cout)[(size_t)row * Nout + col] = f2bf(v);
                else          ((float*)Cout)[(size_t)row * Nout + col] = v;
            }
        }
    }
}

// ---------------- MFMA flash attention, 3-way split-K, table bias -----------
// 768 blocks = 3/CU exactly: b = blk&7, t=blk>>3, part=t%3, qtile=t/3.
// Parts get chunks [0,11) [11,22) [22,32). Bias via LDS table interp.
__global__ __launch_bounds__(512) void attn_mfma(
    const short* __restrict__ qkv,     // [4096][1536] bf16
    const int* __restrict__ dist,      // [B][N][N]
    const float* __restrict__ dist3d,  // [B][N][N]
    const float* __restrict__ demb,    // [128][16] fp32
    const short* __restrict__ Tg,      // [130][16] bf16 rbf table
    float* __restrict__ O_part,        // [3][4096][512] fp32
    float* __restrict__ l_part)        // [3][4096][16]  fp32
{
    const int blk  = blockIdx.x;
    const int b    = blk & 7;
    const int t3   = blk >> 3;
    const int part = t3 % 3;
    const int q0   = (t3 / 3) * 16;
    const int tid  = threadIdx.x;
    const int wave = tid >> 6;
    const int lane = tid & 63;
    const int l16  = lane & 15;
    const int quad = lane >> 4;

    __shared__ short Kc[NH * 16 * 32];  // [h][k16][d32] bf16, 16 KB
    __shared__ short Vc[NH * 16 * 32];  // 16 KB
    __shared__ short Pb[8 * 16 * 32];   // per-wave [q16][k32] bf16, 8 KB
    __shared__ short Tt[130 * 18];      // rbf table, stride-18 pad, 4.7 KB
    __shared__ short Db[128 * 18];      // dist_emb, stride-18 pad, 4.6 KB

    for (int i = tid; i < 8 * 16 * 32; i += 512) Pb[i] = 0;
    for (int i = tid; i < 130 * 16; i += 512) Tt[(i >> 4) * 18 + (i & 15)] = Tg[i];
    for (int i = tid; i < 128 * 16; i += 512) Db[(i >> 4) * 18 + (i & 15)] = f2bf(demb[i]);

    const float scale = 0.17677669529663687f;  // 1/sqrt(32)
    bf16x8 qf[2];
#pragma unroll
    for (int h = 0; h < 2; h++) {
        const int hh = wave * 2 + h;
        qf[h] = *(const bf16x8*)(qkv + (size_t)(b * NN + q0 + l16) * TD + hh * DH + quad * 8);
    }

    f32x4 O[2][2];
    float lsum[2][4];
#pragma unroll
    for (int h = 0; h < 2; h++) {
#pragma unroll
        for (int tt = 0; tt < 2; tt++) O[h][tt] = (f32x4){0.f, 0.f, 0.f, 0.f};
#pragma unroll
        for (int r = 0; r < 4; r++) lsum[h][r] = 0.f;
    }

    const int cbeg = part * 11;
    const int cend = (part == 2) ? 32 : cbeg + 11;

    for (int c = cbeg; c < cend; c++) {
        const int k0 = c * 16;
        __syncthreads();
        // ---- async stage K,V chunk (2048 x 16B chunks) ----
#pragma unroll
        for (int l = 0; l < 4; l++) {
            const int idxb = l * 512 + wave * 64;
            const int idx  = idxb + lane;
            const int kk2  = idx & 1023;
            const int h = kk2 >> 6, k = (kk2 >> 2) & 15, c4 = kk2 & 3;
            const short* src = qkv + (size_t)(b * NN + k0 + k) * TD +
                               DD * (1 + (l >> 1)) + h * 32 + c4 * 8;
            short* dstb = (l < 2 ? (short*)Kc : (short*)Vc) + (size_t)(idxb & 1023) * 8;
            gld_lds16(src, dstb);
        }
        // ---- bias via table interp (overlaps staging latency) ----
        float biasr[2][4];
        {
            const int hh0 = wave * 2, hh1 = hh0 + 1;
#pragma unroll
            for (int r = 0; r < 4; r++) {
                const size_t off = ((size_t)(b * NN) + q0 + quad * 4 + r) * NN + k0 + l16;
                int dc = dist[off];
                dc = min(max(dc, 0), MAXD - 1);
                const float x = dist3d[off] * 6.4f;  // 128/20
                int ii = (int)x; ii = min(ii, 127);
                const float fr = x - (float)ii;
                const float t00 = bf2f(Tt[ii * 18 + hh0]), t01 = bf2f(Tt[ii * 18 + 18 + hh0]);
                const float t10 = bf2f(Tt[ii * 18 + hh1]), t11 = bf2f(Tt[ii * 18 + 18 + hh1]);
                biasr[0][r] = bf2f(Db[dc * 18 + hh0]) + t00 + (t01 - t00) * fr;
                biasr[1][r] = bf2f(Db[dc * 18 + hh1]) + t10 + (t11 - t10) * fr;
            }
        }
        __syncthreads();
        // ---- per-head: QK^T MFMA, bias, exp (no max shift), PV MFMA ----
#pragma unroll
        for (int h = 0; h < 2; h++) {
            const int hh = wave * 2 + h;
            const bf16x8 kf = *(const bf16x8*)&Kc[hh * 512 + l16 * 32 + quad * 8];
            f32x4 s = __builtin_amdgcn_mfma_f32_16x16x32_bf16(
                qf[h], kf, (f32x4){0.f, 0.f, 0.f, 0.f}, 0, 0, 0);
            float pv[4];
#pragma unroll
            for (int r = 0; r < 4; r++) {
                float sv = s[r] * scale + biasr[h][r];
                sv = fminf(sv, 20.f);
                pv[r] = __expf(sv);
                lsum[h][r] += pv[r];
                Pb[wave * 512 + (quad * 4 + r) * 32 + l16] = f2bf(pv[r]);
            }
            const bf16x8 pf = *(const bf16x8*)&Pb[wave * 512 + l16 * 32 + quad * 8];
#pragma unroll
            for (int tt = 0; tt < 2; tt++) {
                bf16x8 vf;
                if (quad < 2) {
#pragma unroll
                    for (int j = 0; j < 8; j++)
                        vf[j] = Vc[hh * 512 + (quad * 8 + j) * 32 + tt * 16 + l16];
                } else {
#pragma unroll
                    for (int j = 0; j < 8; j++) vf[j] = 0;
                }
                O[h][tt] = __builtin_amdgcn_mfma_f32_16x16x32_bf16(pf, vf, O[h][tt], 0, 0, 0);
            }
        }
    }
    // ---- epilogue ----
    const size_t poff = (size_t)part * 4096;
#pragma unroll
    for (int h = 0; h < 2; h++) {
        const int hh = wave * 2 + h;
#pragma unroll
        for (int m = 1; m < 16; m <<= 1)
#pragma unroll
            for (int r = 0; r < 4; r++) lsum[h][r] += __shfl_xor(lsum[h][r], m);
#pragma unroll
        for (int r = 0; r < 4; r++) {
            const size_t row = (size_t)(b * NN + q0 + quad * 4 + r);
#pragma unroll
            for (int tt = 0; tt < 2; tt++)
                O_part[(poff + row) * DD + hh * DH + tt * 16 + l16] = O[h][tt][r];
            if (l16 == 0) l_part[(poff + row) * NH + hh] = lsum[h][r];
        }
    }
}

// ---------------- combine split-K partials -> ctx bf16 ----------------
__global__ __launch_bounds__(256) void attn_combine(
    const float* __restrict__ O_part, const float* __restrict__ l_part,
    short* __restrict__ ctx) {
    const int e = (blockIdx.x * 256 + threadIdx.x) * 4;
    const int row = e >> 9, d = e & 511, h = d >> 5;
    const size_t PO = (size_t)4096 * 512;
    const float4 o0 = *(const float4*)(O_part + e);
    const float4 o1 = *(const float4*)(O_part + PO + e);
    const float4 o2 = *(const float4*)(O_part + 2 * PO + e);
    const int li = row * NH + h;
    const float l = l_part[li] + l_part[4096 * NH + li] + l_part[2 * 4096 * NH + li];
    const float rinv = 1.0f / l;
    short4 o;
    o.x = f2bf((o0.x + o1.x + o2.x) * rinv);
    o.y = f2bf((o0.y + o1.y + o2.y) * rinv);
    o.z = f2bf((o0.z + o1.z + o2.z) * rinv);
    o.w = f2bf((o0.w + o1.w + o2.w) * rinv);
    *(short4*)(ctx + e) = o;
}

extern "C" void kernel_launch(void* const* d_in, const int* in_sizes, int n_in,
                              void* d_out, int out_size, void* d_ws, size_t ws_size,
                              hipStream_t stream) {
    const float* x      = (const float*)d_in[0];
    const int*   dist   = (const int*)d_in[1];
    const float* dist3d = (const float*)d_in[2];
    const float* n1g    = (const float*)d_in[3];
    const float* n1b    = (const float*)d_in[4];
    const float* win    = (const float*)d_in[5];
    const float* bin    = (const float*)d_in[6];
    const float* wo     = (const float*)d_in[7];
    const float* bo     = (const float*)d_in[8];
    const float* demb   = (const float*)d_in[9];
    const float* rbfw   = (const float*)d_in[10];
    const float* rbfb   = (const float*)d_in[11];
    const float* n2g    = (const float*)d_in[12];
    const float* n2b    = (const float*)d_in[13];
    const float* w1     = (const float*)d_in[14];
    const float* b1     = (const float*)d_in[15];
    const float* w2     = (const float*)d_in[16];
    const float* b2     = (const float*)d_in[17];

    char* p = (char*)d_ws;
    short* h_bf   = (short*)p; p += (size_t)4096 * 512 * 2;
    float* h_f    = (float*)p; p += (size_t)4096 * 512 * 4;
    short* qkv_bf = (short*)p; p += (size_t)4096 * 1536 * 2;
    short* ctx_bf = (short*)p; p += (size_t)4096 * 512 * 2;
    float* hres   = (float*)p; p += (size_t)4096 * 512 * 4;
    short* h2_bf  = (short*)p; p += (size_t)4096 * 512 * 2;
    short* win_bf = (short*)p; p += (size_t)1536 * 512 * 2;
    short* wo_bf  = (short*)p; p += (size_t)512 * 512 * 2;
    short* w1_bf  = (short*)p; p += (size_t)2048 * 512 * 2;
    short* w2_bf  = (short*)p; p += (size_t)512 * 2048 * 2;
    short* Tg     = (short*)p; p += (size_t)8192;  // 130*16 bf16 = 4160 B (+pad)
    float* O_part = (float*)p;                     // 24 MB (3 parts)
    short* mid_bf = (short*)p;  // overlays O_part (dead after combine)
    p += (size_t)3 * 4096 * 512 * 4;
    float* l_part = (float*)p; p += (size_t)3 * 4096 * 16 * 4;

    const int M = BB * NN;  // 4096

    cvt_weights<<<dim3(1024, 4), 256, 0, stream>>>(
        win, wo, w1, w2, win_bf, wo_bf, w1_bf, w2_bf,
        1536 * 512, 512 * 512, 2048 * 512, 512 * 2048);
    rbf_table<<<9, 256, 0, stream>>>(rbfw, rbfb, Tg);
    ln_kernel<<<M, 256, 0, stream>>>(x, n1g, n1b, h_bf, h_f);
    gemm_bf16<128, false, false, 1><<<dim3(12, 32), 256, 0, stream>>>(
        h_bf, win_bf, bin, nullptr, qkv_bf, M, TD, DD);
    attn_mfma<<<768, 512, 0, stream>>>(
        qkv_bf, dist, dist3d, demb, Tg, O_part, l_part);
    attn_combine<<<2048, 256, 0, stream>>>(O_part, l_part, ctx_bf);
    gemm_bf16<64, false, true, 0><<<dim3(4, 64), 256, 0, stream>>>(
        ctx_bf, wo_bf, bo, h_f, hres, M, DD, DD);
    ln_kernel<<<M, 256, 0, stream>>>(hres, n2g, n2b, h2_bf, nullptr);
    gemm_bf16<128, true, false, 1><<<dim3(16, 32), 256, 0, stream>>>(
        h2_bf, w1_bf, b1, nullptr, mid_bf, M, 2048, DD);
    gemm_bf16<64, false, true, 0><<<dim3(4, 64), 256, 0, stream>>>(
        mid_bf, w2_bf, b2, hres, (float*)d_out, M, DD, 2048);
}

// Round 9
// 262.197 us; speedup vs baseline: 1.2815x; 1.0191x over previous
//
#include <hip/hip_runtime.h>
#include <hip/hip_bf16.h>
#include <math.h>

#define BB 8
#define NN 512
#define DD 512
#define NH 16
#define DH 32
#define TD 1536
#define NG 32
#define MAXD 128

typedef __attribute__((ext_vector_type(8))) short bf16x8;
typedef __attribute__((ext_vector_type(4))) float f32x4;

__device__ inline short f2bf(float x) {
    __hip_bfloat16 h = __float2bfloat16(x);
    return *reinterpret_cast<short*>(&h);
}
__device__ inline float bf2f(short x) {
    union { unsigned u; float f; } c;
    c.u = ((unsigned)(unsigned short)x) << 16;
    return c.f;
}

// async 16B global->LDS. lds dest must be WAVE-UNIFORM base; lane i lands at base + i*16.
__device__ inline void gld_lds16(const void* g, void* l) {
    __builtin_amdgcn_global_load_lds(
        (const __attribute__((address_space(1))) unsigned int*)g,
        (__attribute__((address_space(3))) unsigned int*)l, 16, 0, 0);
}

// ------- weight fp32 -> bf16 convert (4 arrays) + fused RBF bias table ------
// grid (1024, 5); y==4 builds the 130x16 rbf table on block x==0.
__global__ __launch_bounds__(256) void cvt_weights(
    const float* __restrict__ s0, const float* __restrict__ s1,
    const float* __restrict__ s2, const float* __restrict__ s3,
    short* __restrict__ d0, short* __restrict__ d1,
    short* __restrict__ d2, short* __restrict__ d3,
    const float* __restrict__ rbfw, const float* __restrict__ rbfb,
    short* __restrict__ Tg,
    int n0, int n1, int n2, int n3) {
    if (blockIdx.y == 4) {
        if (blockIdx.x != 0) return;
        const float STEP  = 20.0f / 31.0f;
        const float COEFF = -0.5f / (STEP * STEP);
        for (int idx = threadIdx.x; idx < 130 * 16; idx += 256) {
            const int i = idx >> 4, h = idx & 15;
            const float x = fminf((float)i, 128.0f) * (20.0f / 128.0f);
            float acc = rbfb[h];
#pragma unroll
            for (int g = 0; g < NG; g++) {
                const float t = x - (float)g * STEP;
                acc += __expf(COEFF * t * t) * rbfw[h * NG + g];
            }
            Tg[idx] = f2bf(acc);
        }
        return;
    }
    const float* s; short* d; int n;
    switch (blockIdx.y) {
        case 0: s = s0; d = d0; n = n0; break;
        case 1: s = s1; d = d1; n = n1; break;
        case 2: s = s2; d = d2; n = n2; break;
        default: s = s3; d = d3; n = n3; break;
    }
    const int i = (blockIdx.x * 256 + threadIdx.x) * 4;
    if (i >= n) return;
    const float4 v = *(const float4*)(s + i);
    short4 o;
    o.x = f2bf(v.x); o.y = f2bf(v.y); o.z = f2bf(v.z); o.w = f2bf(v.w);
    *(short4*)(d + i) = o;
}

// ---------------- LayerNorm: bf16 out (+ optional fp32 copy for residual) ---
__global__ __launch_bounds__(256) void ln_kernel(const float* __restrict__ x,
                                                 const float* __restrict__ g,
                                                 const float* __restrict__ b,
                                                 short* __restrict__ out_bf,
                                                 float* __restrict__ out_f) {
    const int row = blockIdx.x;
    const int tid = threadIdx.x;
    const int wave = tid >> 6, lane = tid & 63;
    const float* xr = x + (size_t)row * DD;
    const float v0 = xr[tid], v1 = xr[tid + 256];
    float s = v0 + v1, q = v0 * v0 + v1 * v1;
#pragma unroll
    for (int m = 1; m < 64; m <<= 1) { s += __shfl_xor(s, m); q += __shfl_xor(q, m); }
    __shared__ float ps[8];
    if (lane == 0) { ps[wave] = s; ps[wave + 4] = q; }
    __syncthreads();
    s = ps[0] + ps[1] + ps[2] + ps[3];
    q = ps[4] + ps[5] + ps[6] + ps[7];
    const float mean = s * (1.0f / DD);
    const float var  = q * (1.0f / DD) - mean * mean;
    const float rs   = rsqrtf(var + 1e-5f);
    const float o0 = (v0 - mean) * rs * g[tid] + b[tid];
    const float o1 = (v1 - mean) * rs * g[tid + 256] + b[tid + 256];
    out_bf[(size_t)row * DD + tid]       = f2bf(o0);
    out_bf[(size_t)row * DD + tid + 256] = f2bf(o1);
    if (out_f) {
        out_f[(size_t)row * DD + tid]       = o0;
        out_f[(size_t)row * DD + tid + 256] = o1;
    }
}

// ------- bf16 MFMA GEMM, double-buffered: C = A @ W^T + bias (+gelu)(+res) --
// TM x 128 tile, BK=32. Prefetch next K-tile async while computing current.
template <int TM, bool GELU, bool RES, int OUT>
__global__ __launch_bounds__(256) void gemm_bf16(
    const short* __restrict__ A, const short* __restrict__ Bw,
    const float* __restrict__ bias, const float* __restrict__ res,
    void* __restrict__ Cout, int M, int Nout, int K) {
    const int MI = TM / 32;
    const int bm = blockIdx.y * TM;
    const int bn = blockIdx.x * 128;
    const int tid  = threadIdx.x;
    const int wave = tid >> 6;
    const int lane = tid & 63;
    const int l16  = lane & 15;
    const int quad = lane >> 4;
    const int wr = (wave >> 1) * (TM / 2);
    const int wc = (wave & 1) * 64;

    __shared__ short As[2][TM * 32];
    __shared__ short Bs[2][128 * 32];

    f32x4 acc[MI][4];
#pragma unroll
    for (int i = 0; i < MI; i++)
#pragma unroll
        for (int j = 0; j < 4; j++) acc[i][j] = (f32x4){0.f, 0.f, 0.f, 0.f};

    auto stage = [&](int buf, int k0) {
        const short* Ab = A + (size_t)bm * K + k0;
        const short* Bb = Bw + (size_t)bn * K + k0;
#pragma unroll
        for (int j = 0; j < TM / 64; j++) {
            const int idx = j * 256 + wave * 64 + lane;
            gld_lds16(Ab + (size_t)(idx >> 2) * K + (idx & 3) * 8,
                      &As[buf][(size_t)(j * 256 + wave * 64) * 8]);
        }
#pragma unroll
        for (int j = 0; j < 2; j++) {
            const int idx = j * 256 + wave * 64 + lane;
            gld_lds16(Bb + (size_t)(idx >> 2) * K + (idx & 3) * 8,
                      &Bs[buf][(size_t)(j * 256 + wave * 64) * 8]);
        }
    };
    auto compute = [&](int buf) {
        bf16x8 af[MI], bfr[4];
#pragma unroll
        for (int i = 0; i < MI; i++)
            af[i] = *(const bf16x8*)&As[buf][(wr + i * 16 + l16) * 32 + quad * 8];
#pragma unroll
        for (int j = 0; j < 4; j++)
            bfr[j] = *(const bf16x8*)&Bs[buf][(wc + j * 16 + l16) * 32 + quad * 8];
#pragma unroll
        for (int i = 0; i < MI; i++)
#pragma unroll
            for (int j = 0; j < 4; j++)
                acc[i][j] = __builtin_amdgcn_mfma_f32_16x16x32_bf16(af[i], bfr[j], acc[i][j], 0, 0, 0);
    };

    stage(0, 0);
    __syncthreads();
    int cur = 0;
    for (int k0 = 32; k0 < K; k0 += 32) {
        stage(cur ^ 1, k0);   // async prefetch; lands during compute
        compute(cur);
        __syncthreads();      // drains prefetch + guards buffer reuse
        cur ^= 1;
    }
    compute(cur);

#pragma unroll
    for (int i = 0; i < MI; i++) {
#pragma unroll
        for (int r = 0; r < 4; r++) {
            const int row = bm + wr + i * 16 + quad * 4 + r;
#pragma unroll
            for (int j = 0; j < 4; j++) {
                const int col = bn + wc + j * 16 + l16;
                float v = acc[i][j][r] + bias[col];
                if (GELU) v = 0.5f * v * (1.0f + erff(v * 0.70710678118654752f));
                if (RES)  v += res[(size_t)row * Nout + col];
                if (OUT == 1) ((short*)Cout)[(size_t)row * Nout + col] = f2bf(v);
                else          ((float*)Cout)[(size_t)row * Nout + col] = v;
            }
        }
    }
}

// ---------------- MFMA flash attention, 3-way split-K, table bias -----------
// 768 blocks = 3/CU exactly: b = blk&7, t=blk>>3, part=t%3, qtile=t/3.
__global__ __launch_bounds__(512) void attn_mfma(
    const short* __restrict__ qkv,     // [4096][1536] bf16
    const int* __restrict__ dist,      // [B][N][N]
    const float* __restrict__ dist3d,  // [B][N][N]
    const float* __restrict__ demb,    // [128][16] fp32
    const short* __restrict__ Tg,      // [130][16] bf16 rbf table
    float* __restrict__ O_part,        // [3][4096][512] fp32
    float* __restrict__ l_part)        // [3][4096][16]  fp32
{
    const int blk  = blockIdx.x;
    const int b    = blk & 7;
    const int t3   = blk >> 3;
    const int part = t3 % 3;
    const int q0   = (t3 / 3) * 16;
    const int tid  = threadIdx.x;
    const int wave = tid >> 6;
    const int lane = tid & 63;
    const int l16  = lane & 15;
    const int quad = lane >> 4;

    __shared__ short Kc[NH * 16 * 32];  // [h][k16][d32] bf16, 16 KB
    __shared__ short Vc[NH * 16 * 32];  // 16 KB
    __shared__ short Pb[8 * 16 * 34];   // per-wave [q16][k32 pad34] bf16, 17 KB
    __shared__ short Tt[130 * 18];      // rbf table, stride-18 pad
    __shared__ short Db[128 * 18];      // dist_emb, stride-18 pad

    for (int i = tid; i < 8 * 16 * 34; i += 512) Pb[i] = 0;
    for (int i = tid; i < 130 * 16; i += 512) Tt[(i >> 4) * 18 + (i & 15)] = Tg[i];
    for (int i = tid; i < 128 * 16; i += 512) Db[(i >> 4) * 18 + (i & 15)] = f2bf(demb[i]);

    const float scale = 0.17677669529663687f;  // 1/sqrt(32)
    bf16x8 qf[2];
#pragma unroll
    for (int h = 0; h < 2; h++) {
        const int hh = wave * 2 + h;
        qf[h] = *(const bf16x8*)(qkv + (size_t)(b * NN + q0 + l16) * TD + hh * DH + quad * 8);
    }

    f32x4 O[2][2];
    float lsum[2][4];
#pragma unroll
    for (int h = 0; h < 2; h++) {
#pragma unroll
        for (int tt = 0; tt < 2; tt++) O[h][tt] = (f32x4){0.f, 0.f, 0.f, 0.f};
#pragma unroll
        for (int r = 0; r < 4; r++) lsum[h][r] = 0.f;
    }

    const int cbeg = part * 11;
    const int cend = (part == 2) ? 32 : cbeg + 11;

    for (int c = cbeg; c < cend; c++) {
        const int k0 = c * 16;
        __syncthreads();
        // ---- async stage K,V chunk (2048 x 16B chunks) ----
#pragma unroll
        for (int l = 0; l < 4; l++) {
            const int idxb = l * 512 + wave * 64;
            const int idx  = idxb + lane;
            const int kk2  = idx & 1023;
            const int h = kk2 >> 6, k = (kk2 >> 2) & 15, c4 = kk2 & 3;
            const short* src = qkv + (size_t)(b * NN + k0 + k) * TD +
                               DD * (1 + (l >> 1)) + h * 32 + c4 * 8;
            short* dstb = (l < 2 ? (short*)Kc : (short*)Vc) + (size_t)(idxb & 1023) * 8;
            gld_lds16(src, dstb);
        }
        // ---- bias via table interp (overlaps staging latency) ----
        float biasr[2][4];
        {
            const int hh0 = wave * 2, hh1 = hh0 + 1;
#pragma unroll
            for (int r = 0; r < 4; r++) {
                const size_t off = ((size_t)(b * NN) + q0 + quad * 4 + r) * NN + k0 + l16;
                int dc = dist[off];
                dc = min(max(dc, 0), MAXD - 1);
                const float x = dist3d[off] * 6.4f;  // 128/20
                int ii = (int)x; ii = min(ii, 127);
                const float fr = x - (float)ii;
                const float t00 = bf2f(Tt[ii * 18 + hh0]), t01 = bf2f(Tt[ii * 18 + 18 + hh0]);
                const float t10 = bf2f(Tt[ii * 18 + hh1]), t11 = bf2f(Tt[ii * 18 + 18 + hh1]);
                biasr[0][r] = bf2f(Db[dc * 18 + hh0]) + t00 + (t01 - t00) * fr;
                biasr[1][r] = bf2f(Db[dc * 18 + hh1]) + t10 + (t11 - t10) * fr;
            }
        }
        __syncthreads();
        // ---- per-head: QK^T MFMA, bias, exp (no max shift), PV MFMA ----
#pragma unroll
        for (int h = 0; h < 2; h++) {
            const int hh = wave * 2 + h;
            const bf16x8 kf = *(const bf16x8*)&Kc[hh * 512 + l16 * 32 + quad * 8];
            f32x4 s = __builtin_amdgcn_mfma_f32_16x16x32_bf16(
                qf[h], kf, (f32x4){0.f, 0.f, 0.f, 0.f}, 0, 0, 0);
            float pv[4];
#pragma unroll
            for (int r = 0; r < 4; r++) {
                float sv = s[r] * scale + biasr[h][r];
                sv = fminf(sv, 20.f);
                pv[r] = __expf(sv);
                lsum[h][r] += pv[r];
                Pb[wave * 544 + (quad * 4 + r) * 34 + l16] = f2bf(pv[r]);
            }
            const bf16x8 pf = *(const bf16x8*)&Pb[wave * 544 + l16 * 34 + quad * 8];
#pragma unroll
            for (int tt = 0; tt < 2; tt++) {
                bf16x8 vf;
                if (quad < 2) {
#pragma unroll
                    for (int j = 0; j < 8; j++)
                        vf[j] = Vc[hh * 512 + (quad * 8 + j) * 32 + tt * 16 + l16];
                } else {
#pragma unroll
                    for (int j = 0; j < 8; j++) vf[j] = 0;
                }
                O[h][tt] = __builtin_amdgcn_mfma_f32_16x16x32_bf16(pf, vf, O[h][tt], 0, 0, 0);
            }
        }
    }
    // ---- epilogue ----
    const size_t poff = (size_t)part * 4096;
#pragma unroll
    for (int h = 0; h < 2; h++) {
        const int hh = wave * 2 + h;
#pragma unroll
        for (int m = 1; m < 16; m <<= 1)
#pragma unroll
            for (int r = 0; r < 4; r++) lsum[h][r] += __shfl_xor(lsum[h][r], m);
#pragma unroll
        for (int r = 0; r < 4; r++) {
            const size_t row = (size_t)(b * NN + q0 + quad * 4 + r);
#pragma unroll
            for (int tt = 0; tt < 2; tt++)
                O_part[(poff + row) * DD + hh * DH + tt * 16 + l16] = O[h][tt][r];
            if (l16 == 0) l_part[(poff + row) * NH + hh] = lsum[h][r];
        }
    }
}

// ---------------- combine split-K partials -> ctx bf16 ----------------
__global__ __launch_bounds__(256) void attn_combine(
    const float* __restrict__ O_part, const float* __restrict__ l_part,
    short* __restrict__ ctx) {
    const int e = (blockIdx.x * 256 + threadIdx.x) * 4;
    const int row = e >> 9, d = e & 511, h = d >> 5;
    const size_t PO = (size_t)4096 * 512;
    const float4 o0 = *(const float4*)(O_part + e);
    const float4 o1 = *(const float4*)(O_part + PO + e);
    const float4 o2 = *(const float4*)(O_part + 2 * PO + e);
    const int li = row * NH + h;
    const float l = l_part[li] + l_part[4096 * NH + li] + l_part[2 * 4096 * NH + li];
    const float rinv = 1.0f / l;
    short4 o;
    o.x = f2bf((o0.x + o1.x + o2.x) * rinv);
    o.y = f2bf((o0.y + o1.y + o2.y) * rinv);
    o.z = f2bf((o0.z + o1.z + o2.z) * rinv);
    o.w = f2bf((o0.w + o1.w + o2.w) * rinv);
    *(short4*)(ctx + e) = o;
}

extern "C" void kernel_launch(void* const* d_in, const int* in_sizes, int n_in,
                              void* d_out, int out_size, void* d_ws, size_t ws_size,
                              hipStream_t stream) {
    const float* x      = (const float*)d_in[0];
    const int*   dist   = (const int*)d_in[1];
    const float* dist3d = (const float*)d_in[2];
    const float* n1g    = (const float*)d_in[3];
    const float* n1b    = (const float*)d_in[4];
    const float* win    = (const float*)d_in[5];
    const float* bin    = (const float*)d_in[6];
    const float* wo     = (const float*)d_in[7];
    const float* bo     = (const float*)d_in[8];
    const float* demb   = (const float*)d_in[9];
    const float* rbfw   = (const float*)d_in[10];
    const float* rbfb   = (const float*)d_in[11];
    const float* n2g    = (const float*)d_in[12];
    const float* n2b    = (const float*)d_in[13];
    const float* w1     = (const float*)d_in[14];
    const float* b1     = (const float*)d_in[15];
    const float* w2     = (const float*)d_in[16];
    const float* b2     = (const float*)d_in[17];

    char* p = (char*)d_ws;
    short* h_bf   = (short*)p; p += (size_t)4096 * 512 * 2;
    float* h_f    = (float*)p; p += (size_t)4096 * 512 * 4;
    short* qkv_bf = (short*)p; p += (size_t)4096 * 1536 * 2;
    short* ctx_bf = (short*)p; p += (size_t)4096 * 512 * 2;
    float* hres   = (float*)p; p += (size_t)4096 * 512 * 4;
    short* h2_bf  = (short*)p; p += (size_t)4096 * 512 * 2;
    short* win_bf = (short*)p; p += (size_t)1536 * 512 * 2;
    short* wo_bf  = (short*)p; p += (size_t)512 * 512 * 2;
    short* w1_bf  = (short*)p; p += (size_t)2048 * 512 * 2;
    short* w2_bf  = (short*)p; p += (size_t)512 * 2048 * 2;
    short* Tg     = (short*)p; p += (size_t)8192;  // 130*16 bf16 = 4160 B (+pad)
    float* O_part = (float*)p;                     // 24 MB (3 parts)
    short* mid_bf = (short*)p;  // overlays O_part (dead after combine)
    p += (size_t)3 * 4096 * 512 * 4;
    float* l_part = (float*)p; p += (size_t)3 * 4096 * 16 * 4;

    const int M = BB * NN;  // 4096

    cvt_weights<<<dim3(1024, 5), 256, 0, stream>>>(
        win, wo, w1, w2, win_bf, wo_bf, w1_bf, w2_bf, rbfw, rbfb, Tg,
        1536 * 512, 512 * 512, 2048 * 512, 512 * 2048);
    ln_kernel<<<M, 256, 0, stream>>>(x, n1g, n1b, h_bf, h_f);
    gemm_bf16<64, false, false, 1><<<dim3(12, 64), 256, 0, stream>>>(
        h_bf, win_bf, bin, nullptr, qkv_bf, M, TD, DD);
    attn_mfma<<<768, 512, 0, stream>>>(
        qkv_bf, dist, dist3d, demb, Tg, O_part, l_part);
    attn_combine<<<2048, 256, 0, stream>>>(O_part, l_part, ctx_bf);
    gemm_bf16<64, false, true, 0><<<dim3(4, 64), 256, 0, stream>>>(
        ctx_bf, wo_bf, bo, h_f, hres, M, DD, DD);
    ln_kernel<<<M, 256, 0, stream>>>(hres, n2g, n2b, h2_bf, nullptr);
    gemm_bf16<64, true, false, 1><<<dim3(16, 64), 256, 0, stream>>>(
        h2_bf, w1_bf, b1, nullptr, mid_bf, M, 2048, DD);
    gemm_bf16<64, false, true, 0><<<dim3(4, 64), 256, 0, stream>>>(
        mid_bf, w2_bf, b2, hres, (float*)d_out, M, DD, 2048);
}

// Round 11
// 262.045 us; speedup vs baseline: 1.2823x; 1.0006x over previous
//
#include <hip/hip_runtime.h>
#include <hip/hip_bf16.h>
#include <math.h>

#define BB 8
#define NN 512
#define DD 512
#define NH 16
#define DH 32
#define TD 1536
#define NG 32
#define MAXD 128

typedef __attribute__((ext_vector_type(8))) short bf16x8;
typedef __attribute__((ext_vector_type(4))) float f32x4;

__device__ inline short f2bf(float x) {
    __hip_bfloat16 h = __float2bfloat16(x);
    return *reinterpret_cast<short*>(&h);
}
__device__ inline float bf2f(short x) {
    union { unsigned u; float f; } c;
    c.u = ((unsigned)(unsigned short)x) << 16;
    return c.f;
}

// async 16B global->LDS. lds dest must be WAVE-UNIFORM base; lane i lands at base + i*16.
__device__ inline void gld_lds16(const void* g, void* l) {
    __builtin_amdgcn_global_load_lds(
        (const __attribute__((address_space(1))) unsigned int*)g,
        (__attribute__((address_space(3))) unsigned int*)l, 16, 0, 0);
}

// ------- weight fp32 -> bf16 convert (4 arrays) + fused RBF bias table ------
__global__ __launch_bounds__(256) void cvt_weights(
    const float* __restrict__ s0, const float* __restrict__ s1,
    const float* __restrict__ s2, const float* __restrict__ s3,
    short* __restrict__ d0, short* __restrict__ d1,
    short* __restrict__ d2, short* __restrict__ d3,
    const float* __restrict__ rbfw, const float* __restrict__ rbfb,
    short* __restrict__ Tg,
    int n0, int n1, int n2, int n3) {
    if (blockIdx.y == 4) {
        if (blockIdx.x != 0) return;
        const float STEP  = 20.0f / 31.0f;
        const float COEFF = -0.5f / (STEP * STEP);
        for (int idx = threadIdx.x; idx < 130 * 16; idx += 256) {
            const int i = idx >> 4, h = idx & 15;
            const float x = fminf((float)i, 128.0f) * (20.0f / 128.0f);
            float acc = rbfb[h];
#pragma unroll
            for (int g = 0; g < NG; g++) {
                const float t = x - (float)g * STEP;
                acc += __expf(COEFF * t * t) * rbfw[h * NG + g];
            }
            Tg[idx] = f2bf(acc);
        }
        return;
    }
    const float* s; short* d; int n;
    switch (blockIdx.y) {
        case 0: s = s0; d = d0; n = n0; break;
        case 1: s = s1; d = d1; n = n1; break;
        case 2: s = s2; d = d2; n = n2; break;
        default: s = s3; d = d3; n = n3; break;
    }
    const int i = (blockIdx.x * 256 + threadIdx.x) * 4;
    if (i >= n) return;
    const float4 v = *(const float4*)(s + i);
    short4 o;
    o.x = f2bf(v.x); o.y = f2bf(v.y); o.z = f2bf(v.z); o.w = f2bf(v.w);
    *(short4*)(d + i) = o;
}

// ---------------- LayerNorm: bf16 out (+ optional fp32 copy for residual) ---
__global__ __launch_bounds__(256) void ln_kernel(const float* __restrict__ x,
                                                 const float* __restrict__ g,
                                                 const float* __restrict__ b,
                                                 short* __restrict__ out_bf,
                                                 float* __restrict__ out_f) {
    const int row = blockIdx.x;
    const int tid = threadIdx.x;
    const int wave = tid >> 6, lane = tid & 63;
    const float* xr = x + (size_t)row * DD;
    const float v0 = xr[tid], v1 = xr[tid + 256];
    float s = v0 + v1, q = v0 * v0 + v1 * v1;
#pragma unroll
    for (int m = 1; m < 64; m <<= 1) { s += __shfl_xor(s, m); q += __shfl_xor(q, m); }
    __shared__ float ps[8];
    if (lane == 0) { ps[wave] = s; ps[wave + 4] = q; }
    __syncthreads();
    s = ps[0] + ps[1] + ps[2] + ps[3];
    q = ps[4] + ps[5] + ps[6] + ps[7];
    const float mean = s * (1.0f / DD);
    const float var  = q * (1.0f / DD) - mean * mean;
    const float rs   = rsqrtf(var + 1e-5f);
    const float o0 = (v0 - mean) * rs * g[tid] + b[tid];
    const float o1 = (v1 - mean) * rs * g[tid + 256] + b[tid + 256];
    out_bf[(size_t)row * DD + tid]       = f2bf(o0);
    out_bf[(size_t)row * DD + tid + 256] = f2bf(o1);
    if (out_f) {
        out_f[(size_t)row * DD + tid]       = o0;
        out_f[(size_t)row * DD + tid + 256] = o1;
    }
}

// ------- bf16 MFMA GEMM, double-buffered: C = A @ W^T + bias (+gelu)(+res) --
// TM x 128 tile, BK=32. OUT: 0=f32, 1=bf16, 2=fp32 K-split partial (no bias).
template <int TM, bool GELU, bool RES, int OUT, int SPLIT>
__global__ __launch_bounds__(256) void gemm_bf16(
    const short* __restrict__ A, const short* __restrict__ Bw,
    const float* __restrict__ bias, const float* __restrict__ res,
    void* __restrict__ Cout, int M, int Nout, int K) {
    const int MI = TM / 32;
    const int bm = blockIdx.y * TM;
    const int bn = blockIdx.x * 128;
    const int tid  = threadIdx.x;
    const int wave = tid >> 6;
    const int lane = tid & 63;
    const int l16  = lane & 15;
    const int quad = lane >> 4;
    const int wr = (wave >> 1) * (TM / 2);
    const int wc = (wave & 1) * 64;

    int kbeg = 0, kend = K;
    if (SPLIT > 1) {
        const int z = blockIdx.z;
        const int step = (K / SPLIT) & ~31;
        kbeg = z * step;
        kend = (z == SPLIT - 1) ? K : kbeg + step;
    }

    __shared__ short As[2][TM * 32];
    __shared__ short Bs[2][128 * 32];

    f32x4 acc[MI][4];
#pragma unroll
    for (int i = 0; i < MI; i++)
#pragma unroll
        for (int j = 0; j < 4; j++) acc[i][j] = (f32x4){0.f, 0.f, 0.f, 0.f};

    auto stage = [&](int buf, int k0) {
        const short* Ab = A + (size_t)bm * K + k0;
        const short* Bb = Bw + (size_t)bn * K + k0;
#pragma unroll
        for (int j = 0; j < TM / 64; j++) {
            const int idx = j * 256 + wave * 64 + lane;
            gld_lds16(Ab + (size_t)(idx >> 2) * K + (idx & 3) * 8,
                      &As[buf][(size_t)(j * 256 + wave * 64) * 8]);
        }
#pragma unroll
        for (int j = 0; j < 2; j++) {
            const int idx = j * 256 + wave * 64 + lane;
            gld_lds16(Bb + (size_t)(idx >> 2) * K + (idx & 3) * 8,
                      &Bs[buf][(size_t)(j * 256 + wave * 64) * 8]);
        }
    };
    auto compute = [&](int buf) {
        bf16x8 af[MI], bfr[4];
#pragma unroll
        for (int i = 0; i < MI; i++)
            af[i] = *(const bf16x8*)&As[buf][(wr + i * 16 + l16) * 32 + quad * 8];
#pragma unroll
        for (int j = 0; j < 4; j++)
            bfr[j] = *(const bf16x8*)&Bs[buf][(wc + j * 16 + l16) * 32 + quad * 8];
#pragma unroll
        for (int i = 0; i < MI; i++)
#pragma unroll
            for (int j = 0; j < 4; j++)
                acc[i][j] = __builtin_amdgcn_mfma_f32_16x16x32_bf16(af[i], bfr[j], acc[i][j], 0, 0, 0);
    };

    stage(0, kbeg);
    __syncthreads();
    int cur = 0;
    for (int k0 = kbeg + 32; k0 < kend; k0 += 32) {
        stage(cur ^ 1, k0);
        compute(cur);
        __syncthreads();
        cur ^= 1;
    }
    compute(cur);

#pragma unroll
    for (int i = 0; i < MI; i++) {
#pragma unroll
        for (int r = 0; r < 4; r++) {
            const int row = bm + wr + i * 16 + quad * 4 + r;
#pragma unroll
            for (int j = 0; j < 4; j++) {
                const int col = bn + wc + j * 16 + l16;
                if (OUT == 2) {
                    ((float*)Cout)[(size_t)blockIdx.z * M * Nout +
                                   (size_t)row * Nout + col] = acc[i][j][r];
                } else {
                    float v = acc[i][j][r] + bias[col];
                    if (GELU) v = 0.5f * v * (1.0f + erff(v * 0.70710678118654752f));
                    if (RES)  v += res[(size_t)row * Nout + col];
                    if (OUT == 1) ((short*)Cout)[(size_t)row * Nout + col] = f2bf(v);
                    else          ((float*)Cout)[(size_t)row * Nout + col] = v;
                }
            }
        }
    }
}

// ---------------- ffn2 split-K combine: out = sum parts + bias + res --------
__global__ __launch_bounds__(256) void ffn2_combine(
    const float* __restrict__ part, const float* __restrict__ bias,
    const float* __restrict__ res, float* __restrict__ out) {
    const int e = (blockIdx.x * 256 + threadIdx.x) * 4;
    const int col = e & 511;
    const size_t PO = (size_t)4096 * 512;
    const float4 p0 = *(const float4*)(part + e);
    const float4 p1 = *(const float4*)(part + PO + e);
    const float4 p2 = *(const float4*)(part + 2 * PO + e);
    const float4 rr = *(const float4*)(res + e);
    const float4 bb = *(const float4*)(bias + col);
    float4 o;
    o.x = p0.x + p1.x + p2.x + bb.x + rr.x;
    o.y = p0.y + p1.y + p2.y + bb.y + rr.y;
    o.z = p0.z + p1.z + p2.z + bb.z + rr.z;
    o.w = p0.w + p1.w + p2.w + bb.w + rr.w;
    *(float4*)(out + e) = o;
}

// ---------------- MFMA flash attention, 3-way split-K, table bias -----------
__global__ __launch_bounds__(512) void attn_mfma(
    const short* __restrict__ qkv,
    const int* __restrict__ dist,
    const float* __restrict__ dist3d,
    const float* __restrict__ demb,
    const short* __restrict__ Tg,
    float* __restrict__ O_part,
    float* __restrict__ l_part)
{
    const int blk  = blockIdx.x;
    const int b    = blk & 7;
    const int t3   = blk >> 3;
    const int part = t3 % 3;
    const int q0   = (t3 / 3) * 16;
    const int tid  = threadIdx.x;
    const int wave = tid >> 6;
    const int lane = tid & 63;
    const int l16  = lane & 15;
    const int quad = lane >> 4;

    __shared__ short Kc[NH * 16 * 32];
    __shared__ short Vc[NH * 16 * 32];
    __shared__ short Pb[8 * 16 * 32];
    __shared__ short Tt[130 * 18];
    __shared__ short Db[128 * 18];

    for (int i = tid; i < 8 * 16 * 32; i += 512) Pb[i] = 0;
    for (int i = tid; i < 130 * 16; i += 512) Tt[(i >> 4) * 18 + (i & 15)] = Tg[i];
    for (int i = tid; i < 128 * 16; i += 512) Db[(i >> 4) * 18 + (i & 15)] = f2bf(demb[i]);

    const float scale = 0.17677669529663687f;
    bf16x8 qf[2];
#pragma unroll
    for (int h = 0; h < 2; h++) {
        const int hh = wave * 2 + h;
        qf[h] = *(const bf16x8*)(qkv + (size_t)(b * NN + q0 + l16) * TD + hh * DH + quad * 8);
    }

    f32x4 O[2][2];
    float lsum[2][4];
#pragma unroll
    for (int h = 0; h < 2; h++) {
#pragma unroll
        for (int tt = 0; tt < 2; tt++) O[h][tt] = (f32x4){0.f, 0.f, 0.f, 0.f};
#pragma unroll
        for (int r = 0; r < 4; r++) lsum[h][r] = 0.f;
    }

    const int cbeg = part * 11;
    const int cend = (part == 2) ? 32 : cbeg + 11;

    for (int c = cbeg; c < cend; c++) {
        const int k0 = c * 16;
        __syncthreads();
#pragma unroll
        for (int l = 0; l < 4; l++) {
            const int idxb = l * 512 + wave * 64;
            const int idx  = idxb + lane;
            const int kk2  = idx & 1023;
            const int h = kk2 >> 6, k = (kk2 >> 2) & 15, c4 = kk2 & 3;
            const short* src = qkv + (size_t)(b * NN + k0 + k) * TD +
                               DD * (1 + (l >> 1)) + h * 32 + c4 * 8;
            short* dstb = (l < 2 ? (short*)Kc : (short*)Vc) + (size_t)(idxb & 1023) * 8;
            gld_lds16(src, dstb);
        }
        float biasr[2][4];
        {
            const int hh0 = wave * 2, hh1 = hh0 + 1;
#pragma unroll
            for (int r = 0; r < 4; r++) {
                const size_t off = ((size_t)(b * NN) + q0 + quad * 4 + r) * NN + k0 + l16;
                int dc = dist[off];
                dc = min(max(dc, 0), MAXD - 1);
                const float x = dist3d[off] * 6.4f;
                int ii = (int)x; ii = min(ii, 127);
                const float fr = x - (float)ii;
                const float t00 = bf2f(Tt[ii * 18 + hh0]), t01 = bf2f(Tt[ii * 18 + 18 + hh0]);
                const float t10 = bf2f(Tt[ii * 18 + hh1]), t11 = bf2f(Tt[ii * 18 + 18 + hh1]);
                biasr[0][r] = bf2f(Db[dc * 18 + hh0]) + t00 + (t01 - t00) * fr;
                biasr[1][r] = bf2f(Db[dc * 18 + hh1]) + t10 + (t11 - t10) * fr;
            }
        }
        __syncthreads();
#pragma unroll
        for (int h = 0; h < 2; h++) {
            const int hh = wave * 2 + h;
            const bf16x8 kf = *(const bf16x8*)&Kc[hh * 512 + l16 * 32 + quad * 8];
            f32x4 s = __builtin_amdgcn_mfma_f32_16x16x32_bf16(
                qf[h], kf, (f32x4){0.f, 0.f, 0.f, 0.f}, 0, 0, 0);
            float pv[4];
#pragma unroll
            for (int r = 0; r < 4; r++) {
                float sv = s[r] * scale + biasr[h][r];
                sv = fminf(sv, 20.f);
                pv[r] = __expf(sv);
                lsum[h][r] += pv[r];
                Pb[wave * 512 + (quad * 4 + r) * 32 + l16] = f2bf(pv[r]);
            }
            const bf16x8 pf = *(const bf16x8*)&Pb[wave * 512 + l16 * 32 + quad * 8];
#pragma unroll
            for (int tt = 0; tt < 2; tt++) {
                bf16x8 vf;
                if (quad < 2) {
#pragma unroll
                    for (int j = 0; j < 8; j++)
                        vf[j] = Vc[hh * 512 + (quad * 8 + j) * 32 + tt * 16 + l16];
                } else {
#pragma unroll
                    for (int j = 0; j < 8; j++) vf[j] = 0;
                }
                O[h][tt] = __builtin_amdgcn_mfma_f32_16x16x32_bf16(pf, vf, O[h][tt], 0, 0, 0);
            }
        }
    }
    const size_t poff = (size_t)part * 4096;
#pragma unroll
    for (int h = 0; h < 2; h++) {
        const int hh = wave * 2 + h;
#pragma unroll
        for (int m = 1; m < 16; m <<= 1)
#pragma unroll
            for (int r = 0; r < 4; r++) lsum[h][r] += __shfl_xor(lsum[h][r], m);
#pragma unroll
        for (int r = 0; r < 4; r++) {
            const size_t row = (size_t)(b * NN + q0 + quad * 4 + r);
#pragma unroll
            for (int tt = 0; tt < 2; tt++)
                O_part[(poff + row) * DD + hh * DH + tt * 16 + l16] = O[h][tt][r];
            if (l16 == 0) l_part[(poff + row) * NH + hh] = lsum[h][r];
        }
    }
}

// ---------------- combine attn split-K partials -> ctx bf16 ----------------
__global__ __launch_bounds__(256) void attn_combine(
    const float* __restrict__ O_part, const float* __restrict__ l_part,
    short* __restrict__ ctx) {
    const int e = (blockIdx.x * 256 + threadIdx.x) * 4;
    const int row = e >> 9, d = e & 511, h = d >> 5;
    const size_t PO = (size_t)4096 * 512;
    const float4 o0 = *(const float4*)(O_part + e);
    const float4 o1 = *(const float4*)(O_part + PO + e);
    const float4 o2 = *(const float4*)(O_part + 2 * PO + e);
    const int li = row * NH + h;
    const float l = l_part[li] + l_part[4096 * NH + li] + l_part[2 * 4096 * NH + li];
    const float rinv = 1.0f / l;
    short4 o;
    o.x = f2bf((o0.x + o1.x + o2.x) * rinv);
    o.y = f2bf((o0.y + o1.y + o2.y) * rinv);
    o.z = f2bf((o0.z + o1.z + o2.z) * rinv);
    o.w = f2bf((o0.w + o1.w + o2.w) * rinv);
    *(short4*)(ctx + e) = o;
}

extern "C" void kernel_launch(void* const* d_in, const int* in_sizes, int n_in,
                              void* d_out, int out_size, void* d_ws, size_t ws_size,
                              hipStream_t stream) {
    const float* x      = (const float*)d_in[0];
    const int*   dist   = (const int*)d_in[1];
    const float* dist3d = (const float*)d_in[2];
    const float* n1g    = (const float*)d_in[3];
    const float* n1b    = (const float*)d_in[4];
    const float* win    = (const float*)d_in[5];
    const float* bin    = (const float*)d_in[6];
    const float* wo     = (const float*)d_in[7];
    const float* bo     = (const float*)d_in[8];
    const float* demb   = (const float*)d_in[9];
    const float* rbfw   = (const float*)d_in[10];
    const float* rbfb   = (const float*)d_in[11];
    const float* n2g    = (const float*)d_in[12];
    const float* n2b    = (const float*)d_in[13];
    const float* w1     = (const float*)d_in[14];
    const float* b1     = (const float*)d_in[15];
    const float* w2     = (const float*)d_in[16];
    const float* b2     = (const float*)d_in[17];

    // workspace layout. h_bf/h_f/qkv region (24 MB) is reused as ffn2 fp32
    // partials (f2part) since all three are dead by the ffn2 GEMM.
    char* p = (char*)d_ws;
    short* h_bf   = (short*)p; p += (size_t)4096 * 512 * 2;
    float* h_f    = (float*)p; p += (size_t)4096 * 512 * 4;
    short* qkv_bf = (short*)p; p += (size_t)4096 * 1536 * 2;
    float* f2part = (float*)h_bf;
    short* ctx_bf = (short*)p; p += (size_t)4096 * 512 * 2;
    float* hres   = (float*)p; p += (size_t)4096 * 512 * 4;
    short* h2_bf  = (short*)p; p += (size_t)4096 * 512 * 2;
    short* win_bf = (short*)p; p += (size_t)1536 * 512 * 2;
    short* wo_bf  = (short*)p; p += (size_t)512 * 512 * 2;
    short* w1_bf  = (short*)p; p += (size_t)2048 * 512 * 2;
    short* w2_bf  = (short*)p; p += (size_t)512 * 2048 * 2;
    short* Tg     = (short*)p; p += (size_t)8192;
    float* O_part = (float*)p;
    short* mid_bf = (short*)p;  // overlays O_part (dead after attn_combine)
    p += (size_t)3 * 4096 * 512 * 4;
    float* l_part = (float*)p; p += (size_t)3 * 4096 * 16 * 4;

    const int M = BB * NN;  // 4096

    cvt_weights<<<dim3(1024, 5), 256, 0, stream>>>(
        win, wo, w1, w2, win_bf, wo_bf, w1_bf, w2_bf, rbfw, rbfb, Tg,
        1536 * 512, 512 * 512, 2048 * 512, 512 * 2048);
    ln_kernel<<<M, 256, 0, stream>>>(x, n1g, n1b, h_bf, h_f);
    gemm_bf16<128, false, false, 1, 1><<<dim3(12, 32), 256, 0, stream>>>(
        h_bf, win_bf, bin, nullptr, qkv_bf, M, TD, DD);
    attn_mfma<<<768, 512, 0, stream>>>(
        qkv_bf, dist, dist3d, demb, Tg, O_part, l_part);
    attn_combine<<<2048, 256, 0, stream>>>(O_part, l_part, ctx_bf);
    gemm_bf16<64, false, true, 0, 1><<<dim3(4, 64), 256, 0, stream>>>(
        ctx_bf, wo_bf, bo, h_f, hres, M, DD, DD);
    ln_kernel<<<M, 256, 0, stream>>>(hres, n2g, n2b, h2_bf, nullptr);
    gemm_bf16<128, true, false, 1, 1><<<dim3(16, 32), 256, 0, stream>>>(
        h2_bf, w1_bf, b1, nullptr, mid_bf, M, 2048, DD);
    gemm_bf16<128, false, false, 2, 3><<<dim3(4, 32, 3), 256, 0, stream>>>(
        mid_bf, w2_bf, b2, nullptr, f2part, M, DD, 2048);
    ffn2_combine<<<2048, 256, 0, stream>>>(f2part, b2, hres, (float*)d_out);
}

// Round 12
// 257.777 us; speedup vs baseline: 1.3035x; 1.0166x over previous
//
#include <hip/hip_runtime.h>
#include <hip/hip_bf16.h>
#include <math.h>

#define BB 8
#define NN 512
#define DD 512
#define NH 16
#define DH 32
#define TD 1536
#define NG 32
#define MAXD 128

typedef __attribute__((ext_vector_type(8))) short bf16x8;
typedef __attribute__((ext_vector_type(4))) float f32x4;

__device__ inline short f2bf(float x) {
    __hip_bfloat16 h = __float2bfloat16(x);
    return *reinterpret_cast<short*>(&h);
}
__device__ inline float bf2f(short x) {
    union { unsigned u; float f; } c;
    c.u = ((unsigned)(unsigned short)x) << 16;
    return c.f;
}

// async 16B global->LDS. lds dest must be WAVE-UNIFORM base; lane i lands at base + i*16.
__device__ inline void gld_lds16(const void* g, void* l) {
    __builtin_amdgcn_global_load_lds(
        (const __attribute__((address_space(1))) unsigned int*)g,
        (__attribute__((address_space(3))) unsigned int*)l, 16, 0, 0);
}

// ------- weight fp32 -> bf16 convert (4 arrays) + fused RBF bias table ------
__global__ __launch_bounds__(256) void cvt_weights(
    const float* __restrict__ s0, const float* __restrict__ s1,
    const float* __restrict__ s2, const float* __restrict__ s3,
    short* __restrict__ d0, short* __restrict__ d1,
    short* __restrict__ d2, short* __restrict__ d3,
    const float* __restrict__ rbfw, const float* __restrict__ rbfb,
    short* __restrict__ Tg,
    int n0, int n1, int n2, int n3) {
    if (blockIdx.y == 4) {
        if (blockIdx.x != 0) return;
        const float STEP  = 20.0f / 31.0f;
        const float COEFF = -0.5f / (STEP * STEP);
        for (int idx = threadIdx.x; idx < 130 * 16; idx += 256) {
            const int i = idx >> 4, h = idx & 15;
            const float x = fminf((float)i, 128.0f) * (20.0f / 128.0f);
            float acc = rbfb[h];
#pragma unroll
            for (int g = 0; g < NG; g++) {
                const float t = x - (float)g * STEP;
                acc += __expf(COEFF * t * t) * rbfw[h * NG + g];
            }
            Tg[idx] = f2bf(acc);
        }
        return;
    }
    const float* s; short* d; int n;
    switch (blockIdx.y) {
        case 0: s = s0; d = d0; n = n0; break;
        case 1: s = s1; d = d1; n = n1; break;
        case 2: s = s2; d = d2; n = n2; break;
        default: s = s3; d = d3; n = n3; break;
    }
    const int i = (blockIdx.x * 256 + threadIdx.x) * 4;
    if (i >= n) return;
    const float4 v = *(const float4*)(s + i);
    short4 o;
    o.x = f2bf(v.x); o.y = f2bf(v.y); o.z = f2bf(v.z); o.w = f2bf(v.w);
    *(short4*)(d + i) = o;
}

// ---------------- LayerNorm: bf16 out (+ optional fp32 copy for residual) ---
__global__ __launch_bounds__(256) void ln_kernel(const float* __restrict__ x,
                                                 const float* __restrict__ g,
                                                 const float* __restrict__ b,
                                                 short* __restrict__ out_bf,
                                                 float* __restrict__ out_f) {
    const int row = blockIdx.x;
    const int tid = threadIdx.x;
    const int wave = tid >> 6, lane = tid & 63;
    const float* xr = x + (size_t)row * DD;
    const float v0 = xr[tid], v1 = xr[tid + 256];
    float s = v0 + v1, q = v0 * v0 + v1 * v1;
#pragma unroll
    for (int m = 1; m < 64; m <<= 1) { s += __shfl_xor(s, m); q += __shfl_xor(q, m); }
    __shared__ float ps[8];
    if (lane == 0) { ps[wave] = s; ps[wave + 4] = q; }
    __syncthreads();
    s = ps[0] + ps[1] + ps[2] + ps[3];
    q = ps[4] + ps[5] + ps[6] + ps[7];
    const float mean = s * (1.0f / DD);
    const float var  = q * (1.0f / DD) - mean * mean;
    const float rs   = rsqrtf(var + 1e-5f);
    const float o0 = (v0 - mean) * rs * g[tid] + b[tid];
    const float o1 = (v1 - mean) * rs * g[tid + 256] + b[tid + 256];
    out_bf[(size_t)row * DD + tid]       = f2bf(o0);
    out_bf[(size_t)row * DD + tid + 256] = f2bf(o1);
    if (out_f) {
        out_f[(size_t)row * DD + tid]       = o0;
        out_f[(size_t)row * DD + tid + 256] = o1;
    }
}

// ------- bf16 MFMA GEMM, double-buffered: C = A @ W^T + bias (+gelu)(+res) --
template <int TM, bool GELU, bool RES, int OUT, int SPLIT>
__global__ __launch_bounds__(256) void gemm_bf16(
    const short* __restrict__ A, const short* __restrict__ Bw,
    const float* __restrict__ bias, const float* __restrict__ res,
    void* __restrict__ Cout, int M, int Nout, int K) {
    const int MI = TM / 32;
    const int bm = blockIdx.y * TM;
    const int bn = blockIdx.x * 128;
    const int tid  = threadIdx.x;
    const int wave = tid >> 6;
    const int lane = tid & 63;
    const int l16  = lane & 15;
    const int quad = lane >> 4;
    const int wr = (wave >> 1) * (TM / 2);
    const int wc = (wave & 1) * 64;

    int kbeg = 0, kend = K;
    if (SPLIT > 1) {
        const int z = blockIdx.z;
        const int step = (K / SPLIT) & ~31;
        kbeg = z * step;
        kend = (z == SPLIT - 1) ? K : kbeg + step;
    }

    __shared__ short As[2][TM * 32];
    __shared__ short Bs[2][128 * 32];

    f32x4 acc[MI][4];
#pragma unroll
    for (int i = 0; i < MI; i++)
#pragma unroll
        for (int j = 0; j < 4; j++) acc[i][j] = (f32x4){0.f, 0.f, 0.f, 0.f};

    auto stage = [&](int buf, int k0) {
        const short* Ab = A + (size_t)bm * K + k0;
        const short* Bb = Bw + (size_t)bn * K + k0;
#pragma unroll
        for (int j = 0; j < TM / 64; j++) {
            const int idx = j * 256 + wave * 64 + lane;
            gld_lds16(Ab + (size_t)(idx >> 2) * K + (idx & 3) * 8,
                      &As[buf][(size_t)(j * 256 + wave * 64) * 8]);
        }
#pragma unroll
        for (int j = 0; j < 2; j++) {
            const int idx = j * 256 + wave * 64 + lane;
            gld_lds16(Bb + (size_t)(idx >> 2) * K + (idx & 3) * 8,
                      &Bs[buf][(size_t)(j * 256 + wave * 64) * 8]);
        }
    };
    auto compute = [&](int buf) {
        bf16x8 af[MI], bfr[4];
#pragma unroll
        for (int i = 0; i < MI; i++)
            af[i] = *(const bf16x8*)&As[buf][(wr + i * 16 + l16) * 32 + quad * 8];
#pragma unroll
        for (int j = 0; j < 4; j++)
            bfr[j] = *(const bf16x8*)&Bs[buf][(wc + j * 16 + l16) * 32 + quad * 8];
#pragma unroll
        for (int i = 0; i < MI; i++)
#pragma unroll
            for (int j = 0; j < 4; j++)
                acc[i][j] = __builtin_amdgcn_mfma_f32_16x16x32_bf16(af[i], bfr[j], acc[i][j], 0, 0, 0);
    };

    stage(0, kbeg);
    __syncthreads();
    int cur = 0;
    for (int k0 = kbeg + 32; k0 < kend; k0 += 32) {
        stage(cur ^ 1, k0);
        compute(cur);
        __syncthreads();
        cur ^= 1;
    }
    compute(cur);

#pragma unroll
    for (int i = 0; i < MI; i++) {
#pragma unroll
        for (int r = 0; r < 4; r++) {
            const int row = bm + wr + i * 16 + quad * 4 + r;
#pragma unroll
            for (int j = 0; j < 4; j++) {
                const int col = bn + wc + j * 16 + l16;
                if (OUT == 2) {
                    ((float*)Cout)[(size_t)blockIdx.z * M * Nout +
                                   (size_t)row * Nout + col] = acc[i][j][r];
                } else {
                    float v = acc[i][j][r] + bias[col];
                    if (GELU) v = 0.5f * v * (1.0f + erff(v * 0.70710678118654752f));
                    if (RES)  v += res[(size_t)row * Nout + col];
                    if (OUT == 1) ((short*)Cout)[(size_t)row * Nout + col] = f2bf(v);
                    else          ((float*)Cout)[(size_t)row * Nout + col] = v;
                }
            }
        }
    }
}

// ---------------- ffn2 split-K combine: out = sum parts + bias + res --------
__global__ __launch_bounds__(256) void ffn2_combine(
    const float* __restrict__ part, const float* __restrict__ bias,
    const float* __restrict__ res, float* __restrict__ out) {
    const int e = (blockIdx.x * 256 + threadIdx.x) * 4;
    const int col = e & 511;
    const size_t PO = (size_t)4096 * 512;
    const float4 p0 = *(const float4*)(part + e);
    const float4 p1 = *(const float4*)(part + PO + e);
    const float4 p2 = *(const float4*)(part + 2 * PO + e);
    const float4 rr = *(const float4*)(res + e);
    const float4 bb = *(const float4*)(bias + col);
    float4 o;
    o.x = p0.x + p1.x + p2.x + bb.x + rr.x;
    o.y = p0.y + p1.y + p2.y + bb.y + rr.y;
    o.z = p0.z + p1.z + p2.z + bb.z + rr.z;
    o.w = p0.w + p1.w + p2.w + bb.w + rr.w;
    *(float4*)(out + e) = o;
}

// ---------------- MFMA flash attention, 3-way split-K, table bias -----------
// BARRIER-FREE K-loop: each wave stages and consumes only ITS two heads' K/V
// (no cross-wave LDS sharing in the loop), ordered by explicit s_waitcnt.
__global__ __launch_bounds__(512) void attn_mfma(
    const short* __restrict__ qkv,
    const int* __restrict__ dist,
    const float* __restrict__ dist3d,
    const float* __restrict__ demb,
    const short* __restrict__ Tg,
    float* __restrict__ O_part,
    float* __restrict__ l_part)
{
    const int blk  = blockIdx.x;
    const int b    = blk & 7;
    const int t3   = blk >> 3;
    const int part = t3 % 3;
    const int q0   = (t3 / 3) * 16;
    const int tid  = threadIdx.x;
    const int wave = tid >> 6;
    const int lane = tid & 63;
    const int l16  = lane & 15;
    const int quad = lane >> 4;

    __shared__ short Kc[NH * 16 * 32];
    __shared__ short Vc[NH * 16 * 32];
    __shared__ short Pb[8 * 16 * 32];
    __shared__ short Tt[130 * 18];
    __shared__ short Db[128 * 18];

    for (int i = tid; i < 8 * 16 * 32; i += 512) Pb[i] = 0;
    for (int i = tid; i < 130 * 16; i += 512) Tt[(i >> 4) * 18 + (i & 15)] = Tg[i];
    for (int i = tid; i < 128 * 16; i += 512) Db[(i >> 4) * 18 + (i & 15)] = f2bf(demb[i]);

    const float scale = 0.17677669529663687f;
    bf16x8 qf[2];
#pragma unroll
    for (int h = 0; h < 2; h++) {
        const int hh = wave * 2 + h;
        qf[h] = *(const bf16x8*)(qkv + (size_t)(b * NN + q0 + l16) * TD + hh * DH + quad * 8);
    }

    f32x4 O[2][2];
    float lsum[2][4];
#pragma unroll
    for (int h = 0; h < 2; h++) {
#pragma unroll
        for (int tt = 0; tt < 2; tt++) O[h][tt] = (f32x4){0.f, 0.f, 0.f, 0.f};
#pragma unroll
        for (int r = 0; r < 4; r++) lsum[h][r] = 0.f;
    }

    __syncthreads();  // tables + Pb zero visible to all waves; last barrier.

    const int cbeg = part * 11;
    const int cend = (part == 2) ? 32 : cbeg + 11;

    // per-lane staging role: lane -> (k row, 16B sub-chunk)
    const int sk = lane >> 2;   // 0..15
    const int sc = lane & 3;    // 0..3

    for (int c = cbeg; c < cend; c++) {
        const int k0 = c * 16;
        // ---- per-wave async stage of THIS wave's two heads' K,V ----
        const size_t rowb = (size_t)(b * NN + k0 + sk) * TD + sc * 8;
#pragma unroll
        for (int h = 0; h < 2; h++) {
            const int hh = wave * 2 + h;
            gld_lds16(qkv + rowb + DD + hh * DH,     &Kc[hh * 512]);
            gld_lds16(qkv + rowb + 2 * DD + hh * DH, &Vc[hh * 512]);
        }
        // ---- bias via table interp (overlaps DMA latency) ----
        float biasr[2][4];
        {
            const int hh0 = wave * 2, hh1 = hh0 + 1;
#pragma unroll
            for (int r = 0; r < 4; r++) {
                const size_t off = ((size_t)(b * NN) + q0 + quad * 4 + r) * NN + k0 + l16;
                int dc = dist[off];
                dc = min(max(dc, 0), MAXD - 1);
                const float x = dist3d[off] * 6.4f;
                int ii = (int)x; ii = min(ii, 127);
                const float fr = x - (float)ii;
                const float t00 = bf2f(Tt[ii * 18 + hh0]), t01 = bf2f(Tt[ii * 18 + 18 + hh0]);
                const float t10 = bf2f(Tt[ii * 18 + hh1]), t11 = bf2f(Tt[ii * 18 + 18 + hh1]);
                biasr[0][r] = bf2f(Db[dc * 18 + hh0]) + t00 + (t01 - t00) * fr;
                biasr[1][r] = bf2f(Db[dc * 18 + hh1]) + t10 + (t11 - t10) * fr;
            }
        }
        // wait for this wave's K/V DMA (vmcnt(0)); fences pin IR order.
        asm volatile("" ::: "memory");
        __builtin_amdgcn_s_waitcnt(0x0F70);
        asm volatile("" ::: "memory");
        // ---- per-head: QK^T MFMA, bias, exp (no max shift), PV MFMA ----
#pragma unroll
        for (int h = 0; h < 2; h++) {
            const int hh = wave * 2 + h;
            const bf16x8 kf = *(const bf16x8*)&Kc[hh * 512 + l16 * 32 + quad * 8];
            f32x4 s = __builtin_amdgcn_mfma_f32_16x16x32_bf16(
                qf[h], kf, (f32x4){0.f, 0.f, 0.f, 0.f}, 0, 0, 0);
            float pv[4];
#pragma unroll
            for (int r = 0; r < 4; r++) {
                float sv = s[r] * scale + biasr[h][r];
                sv = fminf(sv, 20.f);
                pv[r] = __expf(sv);
                lsum[h][r] += pv[r];
                Pb[wave * 512 + (quad * 4 + r) * 32 + l16] = f2bf(pv[r]);
            }
            const bf16x8 pf = *(const bf16x8*)&Pb[wave * 512 + l16 * 32 + quad * 8];
#pragma unroll
            for (int tt = 0; tt < 2; tt++) {
                bf16x8 vf;
                if (quad < 2) {
#pragma unroll
                    for (int j = 0; j < 8; j++)
                        vf[j] = Vc[hh * 512 + (quad * 8 + j) * 32 + tt * 16 + l16];
                } else {
#pragma unroll
                    for (int j = 0; j < 8; j++) vf[j] = 0;
                }
                O[h][tt] = __builtin_amdgcn_mfma_f32_16x16x32_bf16(pf, vf, O[h][tt], 0, 0, 0);
            }
        }
        // retire this chunk's LDS reads before next chunk's DMA can overwrite.
        asm volatile("" ::: "memory");
        __builtin_amdgcn_s_waitcnt(0xC07F);  // lgkmcnt(0)
        asm volatile("" ::: "memory");
    }
    const size_t poff = (size_t)part * 4096;
#pragma unroll
    for (int h = 0; h < 2; h++) {
        const int hh = wave * 2 + h;
#pragma unroll
        for (int m = 1; m < 16; m <<= 1)
#pragma unroll
            for (int r = 0; r < 4; r++) lsum[h][r] += __shfl_xor(lsum[h][r], m);
#pragma unroll
        for (int r = 0; r < 4; r++) {
            const size_t row = (size_t)(b * NN + q0 + quad * 4 + r);
#pragma unroll
            for (int tt = 0; tt < 2; tt++)
                O_part[(poff + row) * DD + hh * DH + tt * 16 + l16] = O[h][tt][r];
            if (l16 == 0) l_part[(poff + row) * NH + hh] = lsum[h][r];
        }
    }
}

// ---------------- combine attn split-K partials -> ctx bf16 ----------------
__global__ __launch_bounds__(256) void attn_combine(
    const float* __restrict__ O_part, const float* __restrict__ l_part,
    short* __restrict__ ctx) {
    const int e = (blockIdx.x * 256 + threadIdx.x) * 4;
    const int row = e >> 9, d = e & 511, h = d >> 5;
    const size_t PO = (size_t)4096 * 512;
    const float4 o0 = *(const float4*)(O_part + e);
    const float4 o1 = *(const float4*)(O_part + PO + e);
    const float4 o2 = *(const float4*)(O_part + 2 * PO + e);
    const int li = row * NH + h;
    const float l = l_part[li] + l_part[4096 * NH + li] + l_part[2 * 4096 * NH + li];
    const float rinv = 1.0f / l;
    short4 o;
    o.x = f2bf((o0.x + o1.x + o2.x) * rinv);
    o.y = f2bf((o0.y + o1.y + o2.y) * rinv);
    o.z = f2bf((o0.z + o1.z + o2.z) * rinv);
    o.w = f2bf((o0.w + o1.w + o2.w) * rinv);
    *(short4*)(ctx + e) = o;
}

extern "C" void kernel_launch(void* const* d_in, const int* in_sizes, int n_in,
                              void* d_out, int out_size, void* d_ws, size_t ws_size,
                              hipStream_t stream) {
    const float* x      = (const float*)d_in[0];
    const int*   dist   = (const int*)d_in[1];
    const float* dist3d = (const float*)d_in[2];
    const float* n1g    = (const float*)d_in[3];
    const float* n1b    = (const float*)d_in[4];
    const float* win    = (const float*)d_in[5];
    const float* bin    = (const float*)d_in[6];
    const float* wo     = (const float*)d_in[7];
    const float* bo     = (const float*)d_in[8];
    const float* demb   = (const float*)d_in[9];
    const float* rbfw   = (const float*)d_in[10];
    const float* rbfb   = (const float*)d_in[11];
    const float* n2g    = (const float*)d_in[12];
    const float* n2b    = (const float*)d_in[13];
    const float* w1     = (const float*)d_in[14];
    const float* b1     = (const float*)d_in[15];
    const float* w2     = (const float*)d_in[16];
    const float* b2     = (const float*)d_in[17];

    // workspace layout. h_bf/h_f/qkv region (24 MB) is reused as ffn2 fp32
    // partials (f2part) since all three are dead by the ffn2 GEMM.
    char* p = (char*)d_ws;
    short* h_bf   = (short*)p; p += (size_t)4096 * 512 * 2;
    float* h_f    = (float*)p; p += (size_t)4096 * 512 * 4;
    short* qkv_bf = (short*)p; p += (size_t)4096 * 1536 * 2;
    float* f2part = (float*)h_bf;
    short* ctx_bf = (short*)p; p += (size_t)4096 * 512 * 2;
    float* hres   = (float*)p; p += (size_t)4096 * 512 * 4;
    short* h2_bf  = (short*)p; p += (size_t)4096 * 512 * 2;
    short* win_bf = (short*)p; p += (size_t)1536 * 512 * 2;
    short* wo_bf  = (short*)p; p += (size_t)512 * 512 * 2;
    short* w1_bf  = (short*)p; p += (size_t)2048 * 512 * 2;
    short* w2_bf  = (short*)p; p += (size_t)512 * 2048 * 2;
    short* Tg     = (short*)p; p += (size_t)8192;
    float* O_part = (float*)p;
    short* mid_bf = (short*)p;  // overlays O_part (dead after attn_combine)
    p += (size_t)3 * 4096 * 512 * 4;
    float* l_part = (float*)p; p += (size_t)3 * 4096 * 16 * 4;

    const int M = BB * NN;  // 4096

    cvt_weights<<<dim3(1024, 5), 256, 0, stream>>>(
        win, wo, w1, w2, win_bf, wo_bf, w1_bf, w2_bf, rbfw, rbfb, Tg,
        1536 * 512, 512 * 512, 2048 * 512, 512 * 2048);
    ln_kernel<<<M, 256, 0, stream>>>(x, n1g, n1b, h_bf, h_f);
    gemm_bf16<128, false, false, 1, 1><<<dim3(12, 32), 256, 0, stream>>>(
        h_bf, win_bf, bin, nullptr, qkv_bf, M, TD, DD);
    attn_mfma<<<768, 512, 0, stream>>>(
        qkv_bf, dist, dist3d, demb, Tg, O_part, l_part);
    attn_combine<<<2048, 256, 0, stream>>>(O_part, l_part, ctx_bf);
    gemm_bf16<64, false, true, 0, 1><<<dim3(4, 64), 256, 0, stream>>>(
        ctx_bf, wo_bf, bo, h_f, hres, M, DD, DD);
    ln_kernel<<<M, 256, 0, stream>>>(hres, n2g, n2b, h2_bf, nullptr);
    gemm_bf16<128, true, false, 1, 1><<<dim3(16, 32), 256, 0, stream>>>(
        h2_bf, w1_bf, b1, nullptr, mid_bf, M, 2048, DD);
    gemm_bf16<128, false, false, 2, 3><<<dim3(4, 32, 3), 256, 0, stream>>>(
        mid_bf, w2_bf, b2, nullptr, f2part, M, DD, 2048);
    ffn2_combine<<<2048, 256, 0, stream>>>(f2part, b2, hres, (float*)d_out);
}

// Round 13
// 257.649 us; speedup vs baseline: 1.3042x; 1.0005x over previous
//
#include <hip/hip_runtime.h>
#include <hip/hip_bf16.h>
#include <math.h>

#define BB 8
#define NN 512
#define DD 512
#define NH 16
#define DH 32
#define TD 1536
#define NG 32
#define MAXD 128

typedef __attribute__((ext_vector_type(8))) short bf16x8;
typedef __attribute__((ext_vector_type(4))) float f32x4;

__device__ inline short f2bf(float x) {
    __hip_bfloat16 h = __float2bfloat16(x);
    return *reinterpret_cast<short*>(&h);
}
__device__ inline float bf2f(short x) {
    union { unsigned u; float f; } c;
    c.u = ((unsigned)(unsigned short)x) << 16;
    return c.f;
}

// async 16B global->LDS. lds dest must be WAVE-UNIFORM base; lane i lands at base + i*16.
__device__ inline void gld_lds16(const void* g, void* l) {
    __builtin_amdgcn_global_load_lds(
        (const __attribute__((address_space(1))) unsigned int*)g,
        (__attribute__((address_space(3))) unsigned int*)l, 16, 0, 0);
}

// ------- weight fp32 -> bf16 convert (4 arrays) + fused RBF bias table ------
__global__ __launch_bounds__(256) void cvt_weights(
    const float* __restrict__ s0, const float* __restrict__ s1,
    const float* __restrict__ s2, const float* __restrict__ s3,
    short* __restrict__ d0, short* __restrict__ d1,
    short* __restrict__ d2, short* __restrict__ d3,
    const float* __restrict__ rbfw, const float* __restrict__ rbfb,
    short* __restrict__ Tg,
    int n0, int n1, int n2, int n3) {
    if (blockIdx.y == 4) {
        if (blockIdx.x != 0) return;
        const float STEP  = 20.0f / 31.0f;
        const float COEFF = -0.5f / (STEP * STEP);
        for (int idx = threadIdx.x; idx < 130 * 16; idx += 256) {
            const int i = idx >> 4, h = idx & 15;
            const float x = fminf((float)i, 128.0f) * (20.0f / 128.0f);
            float acc = rbfb[h];
#pragma unroll
            for (int g = 0; g < NG; g++) {
                const float t = x - (float)g * STEP;
                acc += __expf(COEFF * t * t) * rbfw[h * NG + g];
            }
            Tg[idx] = f2bf(acc);
        }
        return;
    }
    const float* s; short* d; int n;
    switch (blockIdx.y) {
        case 0: s = s0; d = d0; n = n0; break;
        case 1: s = s1; d = d1; n = n1; break;
        case 2: s = s2; d = d2; n = n2; break;
        default: s = s3; d = d3; n = n3; break;
    }
    const int i = (blockIdx.x * 256 + threadIdx.x) * 4;
    if (i >= n) return;
    const float4 v = *(const float4*)(s + i);
    short4 o;
    o.x = f2bf(v.x); o.y = f2bf(v.y); o.z = f2bf(v.z); o.w = f2bf(v.w);
    *(short4*)(d + i) = o;
}

// ---------------- LayerNorm: bf16 out ----------------
__global__ __launch_bounds__(256) void ln_kernel(const float* __restrict__ x,
                                                 const float* __restrict__ g,
                                                 const float* __restrict__ b,
                                                 short* __restrict__ out_bf) {
    const int row = blockIdx.x;
    const int tid = threadIdx.x;
    const int wave = tid >> 6, lane = tid & 63;
    const float* xr = x + (size_t)row * DD;
    const float v0 = xr[tid], v1 = xr[tid + 256];
    float s = v0 + v1, q = v0 * v0 + v1 * v1;
#pragma unroll
    for (int m = 1; m < 64; m <<= 1) { s += __shfl_xor(s, m); q += __shfl_xor(q, m); }
    __shared__ float ps[8];
    if (lane == 0) { ps[wave] = s; ps[wave + 4] = q; }
    __syncthreads();
    s = ps[0] + ps[1] + ps[2] + ps[3];
    q = ps[4] + ps[5] + ps[6] + ps[7];
    const float mean = s * (1.0f / DD);
    const float var  = q * (1.0f / DD) - mean * mean;
    const float rs   = rsqrtf(var + 1e-5f);
    out_bf[(size_t)row * DD + tid]       = f2bf((v0 - mean) * rs * g[tid] + b[tid]);
    out_bf[(size_t)row * DD + tid + 256] = f2bf((v1 - mean) * rs * g[tid + 256] + b[tid + 256]);
}

// ------- bf16 MFMA GEMM, double-buffered: C = A @ W^T + bias (+gelu)(+res) --
// TM x 128 tile, BK=32. OUTBF: bf16 vs fp32 out. RES: fp32 residual add.
template <int TM, bool GELU, bool RES, bool OUTBF>
__global__ __launch_bounds__(256) void gemm_bf16(
    const short* __restrict__ A, const short* __restrict__ Bw,
    const float* __restrict__ bias, const float* __restrict__ res,
    void* __restrict__ Cout, int M, int Nout, int K) {
    const int MI = TM / 32;
    const int bm = blockIdx.y * TM;
    const int bn = blockIdx.x * 128;
    const int tid  = threadIdx.x;
    const int wave = tid >> 6;
    const int lane = tid & 63;
    const int l16  = lane & 15;
    const int quad = lane >> 4;
    const int wr = (wave >> 1) * (TM / 2);
    const int wc = (wave & 1) * 64;

    __shared__ short As[2][TM * 32];
    __shared__ short Bs[2][128 * 32];

    f32x4 acc[MI][4];
#pragma unroll
    for (int i = 0; i < MI; i++)
#pragma unroll
        for (int j = 0; j < 4; j++) acc[i][j] = (f32x4){0.f, 0.f, 0.f, 0.f};

    auto stage = [&](int buf, int k0) {
        const short* Ab = A + (size_t)bm * K + k0;
        const short* Bb = Bw + (size_t)bn * K + k0;
#pragma unroll
        for (int j = 0; j < TM / 64; j++) {
            const int idx = j * 256 + wave * 64 + lane;
            gld_lds16(Ab + (size_t)(idx >> 2) * K + (idx & 3) * 8,
                      &As[buf][(size_t)(j * 256 + wave * 64) * 8]);
        }
#pragma unroll
        for (int j = 0; j < 2; j++) {
            const int idx = j * 256 + wave * 64 + lane;
            gld_lds16(Bb + (size_t)(idx >> 2) * K + (idx & 3) * 8,
                      &Bs[buf][(size_t)(j * 256 + wave * 64) * 8]);
        }
    };
    auto compute = [&](int buf) {
        bf16x8 af[MI], bfr[4];
#pragma unroll
        for (int i = 0; i < MI; i++)
            af[i] = *(const bf16x8*)&As[buf][(wr + i * 16 + l16) * 32 + quad * 8];
#pragma unroll
        for (int j = 0; j < 4; j++)
            bfr[j] = *(const bf16x8*)&Bs[buf][(wc + j * 16 + l16) * 32 + quad * 8];
#pragma unroll
        for (int i = 0; i < MI; i++)
#pragma unroll
            for (int j = 0; j < 4; j++)
                acc[i][j] = __builtin_amdgcn_mfma_f32_16x16x32_bf16(af[i], bfr[j], acc[i][j], 0, 0, 0);
    };

    stage(0, 0);
    __syncthreads();
    int cur = 0;
    for (int k0 = 32; k0 < K; k0 += 32) {
        stage(cur ^ 1, k0);
        compute(cur);
        __syncthreads();
        cur ^= 1;
    }
    compute(cur);

#pragma unroll
    for (int i = 0; i < MI; i++) {
#pragma unroll
        for (int r = 0; r < 4; r++) {
            const int row = bm + wr + i * 16 + quad * 4 + r;
#pragma unroll
            for (int j = 0; j < 4; j++) {
                const int col = bn + wc + j * 16 + l16;
                float v = acc[i][j][r] + bias[col];
                if (GELU) v = 0.5f * v * (1.0f + erff(v * 0.70710678118654752f));
                if (RES)  v += res[(size_t)row * Nout + col];
                if (OUTBF) ((short*)Cout)[(size_t)row * Nout + col] = f2bf(v);
                else       ((float*)Cout)[(size_t)row * Nout + col] = v;
            }
        }
    }
}

// ------- out-proj GEMM with FUSED split-K combine on the A operand ---------
// hres = (combine(O_part)/l) @ Wo^T + bo + res(h_bf).  TM=64, TN=128, BK=32.
__global__ __launch_bounds__(256) void gemm_op(
    const short* __restrict__ Opart,   // [3][4096][512] bf16 unnormalized
    const float* __restrict__ lpart,   // [3][4096][16] fp32
    const short* __restrict__ Bw,      // wo_bf [512][512]
    const float* __restrict__ bias,    // bo
    const short* __restrict__ resb,    // h_bf bf16 [4096][512]
    float* __restrict__ Cout) {        // hres fp32
    const int bm = blockIdx.y * 64;
    const int bn = blockIdx.x * 128;
    const int tid  = threadIdx.x;
    const int wave = tid >> 6;
    const int lane = tid & 63;
    const int l16  = lane & 15;
    const int quad = lane >> 4;
    const int wr = (wave >> 1) * 32;
    const int wc = (wave & 1) * 64;
    const size_t PO = (size_t)4096 * 512;

    __shared__ short As[2][64 * 32];
    __shared__ short Bs[2][128 * 32];
    __shared__ float Lr[64 * 16];

    // rinv prologue: Lr[r][h] = 1 / sum_p l_part[p][bm+r][h]
    for (int i = tid; i < 64 * 16; i += 256) {
        const int idx = (bm + (i >> 4)) * 16 + (i & 15);
        Lr[i] = 1.0f / (lpart[idx] + lpart[4096 * 16 + idx] + lpart[2 * 4096 * 16 + idx]);
    }
    __syncthreads();

    f32x4 acc[2][4];
#pragma unroll
    for (int i = 0; i < 2; i++)
#pragma unroll
        for (int j = 0; j < 4; j++) acc[i][j] = (f32x4){0.f, 0.f, 0.f, 0.f};

    const int arow = tid >> 2;          // 0..63
    const int acb  = (tid & 3) * 8;     // 0,8,16,24

    auto stageA = [&](int buf, int k0) {
        const size_t base = (size_t)(bm + arow) * 512 + k0 + acb;
        const bf16x8 a0 = *(const bf16x8*)(Opart + base);
        const bf16x8 a1 = *(const bf16x8*)(Opart + PO + base);
        const bf16x8 a2 = *(const bf16x8*)(Opart + 2 * PO + base);
        const float rv = Lr[arow * 16 + (k0 >> 5)];
        bf16x8 o;
#pragma unroll
        for (int e = 0; e < 8; e++)
            o[e] = f2bf((bf2f(a0[e]) + bf2f(a1[e]) + bf2f(a2[e])) * rv);
        *(bf16x8*)&As[buf][arow * 32 + acb] = o;
    };
    auto stageB = [&](int buf, int k0) {
        const short* Bb = Bw + (size_t)bn * 512 + k0;
#pragma unroll
        for (int j = 0; j < 2; j++) {
            const int idx = j * 256 + wave * 64 + lane;
            gld_lds16(Bb + (size_t)(idx >> 2) * 512 + (idx & 3) * 8,
                      &Bs[buf][(size_t)(j * 256 + wave * 64) * 8]);
        }
    };
    auto compute = [&](int buf) {
        bf16x8 af[2], bfr[4];
#pragma unroll
        for (int i = 0; i < 2; i++)
            af[i] = *(const bf16x8*)&As[buf][(wr + i * 16 + l16) * 32 + quad * 8];
#pragma unroll
        for (int j = 0; j < 4; j++)
            bfr[j] = *(const bf16x8*)&Bs[buf][(wc + j * 16 + l16) * 32 + quad * 8];
#pragma unroll
        for (int i = 0; i < 2; i++)
#pragma unroll
            for (int j = 0; j < 4; j++)
                acc[i][j] = __builtin_amdgcn_mfma_f32_16x16x32_bf16(af[i], bfr[j], acc[i][j], 0, 0, 0);
    };

    stageB(0, 0);
    stageA(0, 0);
    __syncthreads();
    int cur = 0;
    for (int k0 = 32; k0 < 512; k0 += 32) {
        stageB(cur ^ 1, k0);
        stageA(cur ^ 1, k0);
        compute(cur);
        __syncthreads();
        cur ^= 1;
    }
    compute(cur);

#pragma unroll
    for (int i = 0; i < 2; i++) {
#pragma unroll
        for (int r = 0; r < 4; r++) {
            const int row = bm + wr + i * 16 + quad * 4 + r;
#pragma unroll
            for (int j = 0; j < 4; j++) {
                const int col = bn + wc + j * 16 + l16;
                float v = acc[i][j][r] + bias[col] + bf2f(resb[(size_t)row * 512 + col]);
                Cout[(size_t)row * 512 + col] = v;
            }
        }
    }
}

// ---------------- MFMA flash attention, 3-way split-K, table bias -----------
// BARRIER-FREE K-loop: each wave stages and consumes only ITS two heads' K/V.
__global__ __launch_bounds__(512) void attn_mfma(
    const short* __restrict__ qkv,
    const int* __restrict__ dist,
    const float* __restrict__ dist3d,
    const float* __restrict__ demb,
    const short* __restrict__ Tg,
    short* __restrict__ O_part,        // [3][4096][512] bf16 unnormalized
    float* __restrict__ l_part)        // [3][4096][16]  fp32
{
    const int blk  = blockIdx.x;
    const int b    = blk & 7;
    const int t3   = blk >> 3;
    const int part = t3 % 3;
    const int q0   = (t3 / 3) * 16;
    const int tid  = threadIdx.x;
    const int wave = tid >> 6;
    const int lane = tid & 63;
    const int l16  = lane & 15;
    const int quad = lane >> 4;

    __shared__ short Kc[NH * 16 * 32];
    __shared__ short Vc[NH * 16 * 32];
    __shared__ short Pb[8 * 16 * 32];
    __shared__ short Tt[130 * 18];
    __shared__ short Db[128 * 18];

    for (int i = tid; i < 8 * 16 * 32; i += 512) Pb[i] = 0;
    for (int i = tid; i < 130 * 16; i += 512) Tt[(i >> 4) * 18 + (i & 15)] = Tg[i];
    for (int i = tid; i < 128 * 16; i += 512) Db[(i >> 4) * 18 + (i & 15)] = f2bf(demb[i]);

    const float scale = 0.17677669529663687f;
    bf16x8 qf[2];
#pragma unroll
    for (int h = 0; h < 2; h++) {
        const int hh = wave * 2 + h;
        qf[h] = *(const bf16x8*)(qkv + (size_t)(b * NN + q0 + l16) * TD + hh * DH + quad * 8);
    }

    f32x4 O[2][2];
    float lsum[2][4];
#pragma unroll
    for (int h = 0; h < 2; h++) {
#pragma unroll
        for (int tt = 0; tt < 2; tt++) O[h][tt] = (f32x4){0.f, 0.f, 0.f, 0.f};
#pragma unroll
        for (int r = 0; r < 4; r++) lsum[h][r] = 0.f;
    }

    __syncthreads();  // tables + Pb zero visible; last barrier.

    const int cbeg = part * 11;
    const int cend = (part == 2) ? 32 : cbeg + 11;

    const int sk = lane >> 2;
    const int sc = lane & 3;

    for (int c = cbeg; c < cend; c++) {
        const int k0 = c * 16;
        const size_t rowb = (size_t)(b * NN + k0 + sk) * TD + sc * 8;
#pragma unroll
        for (int h = 0; h < 2; h++) {
            const int hh = wave * 2 + h;
            gld_lds16(qkv + rowb + DD + hh * DH,     &Kc[hh * 512]);
            gld_lds16(qkv + rowb + 2 * DD + hh * DH, &Vc[hh * 512]);
        }
        float biasr[2][4];
        {
            const int hh0 = wave * 2, hh1 = hh0 + 1;
#pragma unroll
            for (int r = 0; r < 4; r++) {
                const size_t off = ((size_t)(b * NN) + q0 + quad * 4 + r) * NN + k0 + l16;
                int dc = dist[off];
                dc = min(max(dc, 0), MAXD - 1);
                const float x = dist3d[off] * 6.4f;
                int ii = (int)x; ii = min(ii, 127);
                const float fr = x - (float)ii;
                const float t00 = bf2f(Tt[ii * 18 + hh0]), t01 = bf2f(Tt[ii * 18 + 18 + hh0]);
                const float t10 = bf2f(Tt[ii * 18 + hh1]), t11 = bf2f(Tt[ii * 18 + 18 + hh1]);
                biasr[0][r] = bf2f(Db[dc * 18 + hh0]) + t00 + (t01 - t00) * fr;
                biasr[1][r] = bf2f(Db[dc * 18 + hh1]) + t10 + (t11 - t10) * fr;
            }
        }
        asm volatile("" ::: "memory");
        __builtin_amdgcn_s_waitcnt(0x0F70);  // vmcnt(0)
        asm volatile("" ::: "memory");
#pragma unroll
        for (int h = 0; h < 2; h++) {
            const int hh = wave * 2 + h;
            const bf16x8 kf = *(const bf16x8*)&Kc[hh * 512 + l16 * 32 + quad * 8];
            f32x4 s = __builtin_amdgcn_mfma_f32_16x16x32_bf16(
                qf[h], kf, (f32x4){0.f, 0.f, 0.f, 0.f}, 0, 0, 0);
            float pv[4];
#pragma unroll
            for (int r = 0; r < 4; r++) {
                float sv = s[r] * scale + biasr[h][r];
                sv = fminf(sv, 20.f);
                pv[r] = __expf(sv);
                lsum[h][r] += pv[r];
                Pb[wave * 512 + (quad * 4 + r) * 32 + l16] = f2bf(pv[r]);
            }
            const bf16x8 pf = *(const bf16x8*)&Pb[wave * 512 + l16 * 32 + quad * 8];
#pragma unroll
            for (int tt = 0; tt < 2; tt++) {
                bf16x8 vf;
                if (quad < 2) {
#pragma unroll
                    for (int j = 0; j < 8; j++)
                        vf[j] = Vc[hh * 512 + (quad * 8 + j) * 32 + tt * 16 + l16];
                } else {
#pragma unroll
                    for (int j = 0; j < 8; j++) vf[j] = 0;
                }
                O[h][tt] = __builtin_amdgcn_mfma_f32_16x16x32_bf16(pf, vf, O[h][tt], 0, 0, 0);
            }
        }
        asm volatile("" ::: "memory");
        __builtin_amdgcn_s_waitcnt(0xC07F);  // lgkmcnt(0)
        asm volatile("" ::: "memory");
    }
    const size_t poff = (size_t)part * 4096;
#pragma unroll
    for (int h = 0; h < 2; h++) {
        const int hh = wave * 2 + h;
#pragma unroll
        for (int m = 1; m < 16; m <<= 1)
#pragma unroll
            for (int r = 0; r < 4; r++) lsum[h][r] += __shfl_xor(lsum[h][r], m);
#pragma unroll
        for (int r = 0; r < 4; r++) {
            const size_t row = (size_t)(b * NN + q0 + quad * 4 + r);
#pragma unroll
            for (int tt = 0; tt < 2; tt++)
                O_part[(poff + row) * DD + hh * DH + tt * 16 + l16] = f2bf(O[h][tt][r]);
            if (l16 == 0) l_part[(poff + row) * NH + hh] = lsum[h][r];
        }
    }
}

extern "C" void kernel_launch(void* const* d_in, const int* in_sizes, int n_in,
                              void* d_out, int out_size, void* d_ws, size_t ws_size,
                              hipStream_t stream) {
    const float* x      = (const float*)d_in[0];
    const int*   dist   = (const int*)d_in[1];
    const float* dist3d = (const float*)d_in[2];
    const float* n1g    = (const float*)d_in[3];
    const float* n1b    = (const float*)d_in[4];
    const float* win    = (const float*)d_in[5];
    const float* bin    = (const float*)d_in[6];
    const float* wo     = (const float*)d_in[7];
    const float* bo     = (const float*)d_in[8];
    const float* demb   = (const float*)d_in[9];
    const float* rbfw   = (const float*)d_in[10];
    const float* rbfb   = (const float*)d_in[11];
    const float* n2g    = (const float*)d_in[12];
    const float* n2b    = (const float*)d_in[13];
    const float* w1     = (const float*)d_in[14];
    const float* b1     = (const float*)d_in[15];
    const float* w2     = (const float*)d_in[16];
    const float* b2     = (const float*)d_in[17];

    // workspace. Opart region (16 MB) is reused by mid_bf (ffn1 output) since
    // O_part+l_part are dead after gemm_op, which runs before ffn1.
    char* p = (char*)d_ws;
    short* h_bf   = (short*)p; p += (size_t)4096 * 512 * 2;       // 4 MB
    short* qkv_bf = (short*)p; p += (size_t)4096 * 1536 * 2;      // 12 MB
    float* hres   = (float*)p; p += (size_t)4096 * 512 * 4;       // 8 MB
    short* h2_bf  = (short*)p; p += (size_t)4096 * 512 * 2;       // 4 MB
    short* win_bf = (short*)p; p += (size_t)1536 * 512 * 2;
    short* wo_bf  = (short*)p; p += (size_t)512 * 512 * 2;
    short* w1_bf  = (short*)p; p += (size_t)2048 * 512 * 2;
    short* w2_bf  = (short*)p; p += (size_t)512 * 2048 * 2;
    short* Tg     = (short*)p; p += (size_t)8192;
    short* O_part = (short*)p;                                    // 12 MB used
    short* mid_bf = (short*)p;                                    // 16 MB used
    p += (size_t)4096 * 2048 * 2;                                 // 16 MB region
    float* l_part = (float*)p; p += (size_t)3 * 4096 * 16 * 4;

    const int M = BB * NN;  // 4096

    cvt_weights<<<dim3(1024, 5), 256, 0, stream>>>(
        win, wo, w1, w2, win_bf, wo_bf, w1_bf, w2_bf, rbfw, rbfb, Tg,
        1536 * 512, 512 * 512, 2048 * 512, 512 * 2048);
    ln_kernel<<<M, 256, 0, stream>>>(x, n1g, n1b, h_bf);
    gemm_bf16<128, false, false, true><<<dim3(12, 32), 256, 0, stream>>>(
        h_bf, win_bf, bin, nullptr, qkv_bf, M, TD, DD);
    attn_mfma<<<768, 512, 0, stream>>>(
        qkv_bf, dist, dist3d, demb, Tg, O_part, l_part);
    gemm_op<<<dim3(4, 64), 256, 0, stream>>>(
        O_part, l_part, wo_bf, bo, h_bf, hres);
    ln_kernel<<<M, 256, 0, stream>>>(hres, n2g, n2b, h2_bf);
    gemm_bf16<128, true, false, true><<<dim3(16, 32), 256, 0, stream>>>(
        h2_bf, w1_bf, b1, nullptr, mid_bf, M, 2048, DD);
    gemm_bf16<64, false, true, false><<<dim3(4, 64), 256, 0, stream>>>(
        mid_bf, w2_bf, b2, hres, (float*)d_out, M, DD, 2048);
}

// Round 14
// 249.419 us; speedup vs baseline: 1.3472x; 1.0330x over previous
//
#include <hip/hip_runtime.h>
#include <hip/hip_bf16.h>
#include <math.h>

#define BB 8
#define NN 512
#define DD 512
#define NH 16
#define DH 32
#define TD 1536
#define NG 32
#define MAXD 128

typedef __attribute__((ext_vector_type(8))) short bf16x8;
typedef __attribute__((ext_vector_type(4))) float f32x4;

__device__ inline short f2bf(float x) {
    __hip_bfloat16 h = __float2bfloat16(x);
    return *reinterpret_cast<short*>(&h);
}
__device__ inline float bf2f(short x) {
    union { unsigned u; float f; } c;
    c.u = ((unsigned)(unsigned short)x) << 16;
    return c.f;
}

// async 16B global->LDS. lds dest must be WAVE-UNIFORM base; lane i lands at base + i*16.
__device__ inline void gld_lds16(const void* g, void* l) {
    __builtin_amdgcn_global_load_lds(
        (const __attribute__((address_space(1))) unsigned int*)g,
        (__attribute__((address_space(3))) unsigned int*)l, 16, 0, 0);
}

// ------- weight fp32 -> bf16 convert (4 arrays) + fused RBF bias table ------
// Table: 193 nodes on [0,20] (nearest-neighbor lookup; |f'|*delta/2 ~ 3e-3).
__global__ __launch_bounds__(256) void cvt_weights(
    const float* __restrict__ s0, const float* __restrict__ s1,
    const float* __restrict__ s2, const float* __restrict__ s3,
    short* __restrict__ d0, short* __restrict__ d1,
    short* __restrict__ d2, short* __restrict__ d3,
    const float* __restrict__ rbfw, const float* __restrict__ rbfb,
    short* __restrict__ Tg,
    int n0, int n1, int n2, int n3) {
    if (blockIdx.y == 4) {
        if (blockIdx.x != 0) return;
        const float STEP  = 20.0f / 31.0f;
        const float COEFF = -0.5f / (STEP * STEP);
        for (int idx = threadIdx.x; idx < 194 * 16; idx += 256) {
            const int i = idx >> 4, h = idx & 15;
            const float x = fminf((float)i, 192.0f) * (20.0f / 192.0f);
            float acc = rbfb[h];
#pragma unroll
            for (int g = 0; g < NG; g++) {
                const float t = x - (float)g * STEP;
                acc += __expf(COEFF * t * t) * rbfw[h * NG + g];
            }
            Tg[idx] = f2bf(acc);
        }
        return;
    }
    const float* s; short* d; int n;
    switch (blockIdx.y) {
        case 0: s = s0; d = d0; n = n0; break;
        case 1: s = s1; d = d1; n = n1; break;
        case 2: s = s2; d = d2; n = n2; break;
        default: s = s3; d = d3; n = n3; break;
    }
    const int i = (blockIdx.x * 256 + threadIdx.x) * 4;
    if (i >= n) return;
    const float4 v = *(const float4*)(s + i);
    short4 o;
    o.x = f2bf(v.x); o.y = f2bf(v.y); o.z = f2bf(v.z); o.w = f2bf(v.w);
    *(short4*)(d + i) = o;
}

// ---------------- LayerNorm: bf16 out ----------------
__global__ __launch_bounds__(256) void ln_kernel(const float* __restrict__ x,
                                                 const float* __restrict__ g,
                                                 const float* __restrict__ b,
                                                 short* __restrict__ out_bf) {
    const int row = blockIdx.x;
    const int tid = threadIdx.x;
    const int wave = tid >> 6, lane = tid & 63;
    const float* xr = x + (size_t)row * DD;
    const float v0 = xr[tid], v1 = xr[tid + 256];
    float s = v0 + v1, q = v0 * v0 + v1 * v1;
#pragma unroll
    for (int m = 1; m < 64; m <<= 1) { s += __shfl_xor(s, m); q += __shfl_xor(q, m); }
    __shared__ float ps[8];
    if (lane == 0) { ps[wave] = s; ps[wave + 4] = q; }
    __syncthreads();
    s = ps[0] + ps[1] + ps[2] + ps[3];
    q = ps[4] + ps[5] + ps[6] + ps[7];
    const float mean = s * (1.0f / DD);
    const float var  = q * (1.0f / DD) - mean * mean;
    const float rs   = rsqrtf(var + 1e-5f);
    out_bf[(size_t)row * DD + tid]       = f2bf((v0 - mean) * rs * g[tid] + b[tid]);
    out_bf[(size_t)row * DD + tid + 256] = f2bf((v1 - mean) * rs * g[tid + 256] + b[tid + 256]);
}

// ------- bf16 MFMA GEMM, double-buffered: C = A @ W^T + bias (+gelu)(+res) --
template <int TM, bool GELU, bool RES, bool OUTBF>
__global__ __launch_bounds__(256) void gemm_bf16(
    const short* __restrict__ A, const short* __restrict__ Bw,
    const float* __restrict__ bias, const float* __restrict__ res,
    void* __restrict__ Cout, int M, int Nout, int K) {
    const int MI = TM / 32;
    const int bm = blockIdx.y * TM;
    const int bn = blockIdx.x * 128;
    const int tid  = threadIdx.x;
    const int wave = tid >> 6;
    const int lane = tid & 63;
    const int l16  = lane & 15;
    const int quad = lane >> 4;
    const int wr = (wave >> 1) * (TM / 2);
    const int wc = (wave & 1) * 64;

    __shared__ short As[2][TM * 32];
    __shared__ short Bs[2][128 * 32];

    f32x4 acc[MI][4];
#pragma unroll
    for (int i = 0; i < MI; i++)
#pragma unroll
        for (int j = 0; j < 4; j++) acc[i][j] = (f32x4){0.f, 0.f, 0.f, 0.f};

    auto stage = [&](int buf, int k0) {
        const short* Ab = A + (size_t)bm * K + k0;
        const short* Bb = Bw + (size_t)bn * K + k0;
#pragma unroll
        for (int j = 0; j < TM / 64; j++) {
            const int idx = j * 256 + wave * 64 + lane;
            gld_lds16(Ab + (size_t)(idx >> 2) * K + (idx & 3) * 8,
                      &As[buf][(size_t)(j * 256 + wave * 64) * 8]);
        }
#pragma unroll
        for (int j = 0; j < 2; j++) {
            const int idx = j * 256 + wave * 64 + lane;
            gld_lds16(Bb + (size_t)(idx >> 2) * K + (idx & 3) * 8,
                      &Bs[buf][(size_t)(j * 256 + wave * 64) * 8]);
        }
    };
    auto compute = [&](int buf) {
        bf16x8 af[MI], bfr[4];
#pragma unroll
        for (int i = 0; i < MI; i++)
            af[i] = *(const bf16x8*)&As[buf][(wr + i * 16 + l16) * 32 + quad * 8];
#pragma unroll
        for (int j = 0; j < 4; j++)
            bfr[j] = *(const bf16x8*)&Bs[buf][(wc + j * 16 + l16) * 32 + quad * 8];
#pragma unroll
        for (int i = 0; i < MI; i++)
#pragma unroll
            for (int j = 0; j < 4; j++)
                acc[i][j] = __builtin_amdgcn_mfma_f32_16x16x32_bf16(af[i], bfr[j], acc[i][j], 0, 0, 0);
    };

    stage(0, 0);
    __syncthreads();
    int cur = 0;
    for (int k0 = 32; k0 < K; k0 += 32) {
        stage(cur ^ 1, k0);
        compute(cur);
        __syncthreads();
        cur ^= 1;
    }
    compute(cur);

#pragma unroll
    for (int i = 0; i < MI; i++) {
#pragma unroll
        for (int r = 0; r < 4; r++) {
            const int row = bm + wr + i * 16 + quad * 4 + r;
#pragma unroll
            for (int j = 0; j < 4; j++) {
                const int col = bn + wc + j * 16 + l16;
                float v = acc[i][j][r] + bias[col];
                if (GELU) v = 0.5f * v * (1.0f + erff(v * 0.70710678118654752f));
                if (RES)  v += res[(size_t)row * Nout + col];
                if (OUTBF) ((short*)Cout)[(size_t)row * Nout + col] = f2bf(v);
                else       ((float*)Cout)[(size_t)row * Nout + col] = v;
            }
        }
    }
}

// ------- out-proj GEMM with FUSED split-K combine on the A operand ---------
__global__ __launch_bounds__(256) void gemm_op(
    const short* __restrict__ Opart,   // [3][4096][512] bf16 unnormalized
    const float* __restrict__ lpart,   // [3][4096][16] fp32
    const short* __restrict__ Bw,      // wo_bf [512][512]
    const float* __restrict__ bias,    // bo
    const short* __restrict__ resb,    // h_bf bf16 [4096][512]
    float* __restrict__ Cout) {        // hres fp32
    const int bm = blockIdx.y * 64;
    const int bn = blockIdx.x * 128;
    const int tid  = threadIdx.x;
    const int wave = tid >> 6;
    const int lane = tid & 63;
    const int l16  = lane & 15;
    const int quad = lane >> 4;
    const int wr = (wave >> 1) * 32;
    const int wc = (wave & 1) * 64;
    const size_t PO = (size_t)4096 * 512;

    __shared__ short As[2][64 * 32];
    __shared__ short Bs[2][128 * 32];
    __shared__ float Lr[64 * 16];

    for (int i = tid; i < 64 * 16; i += 256) {
        const int idx = (bm + (i >> 4)) * 16 + (i & 15);
        Lr[i] = 1.0f / (lpart[idx] + lpart[4096 * 16 + idx] + lpart[2 * 4096 * 16 + idx]);
    }
    __syncthreads();

    f32x4 acc[2][4];
#pragma unroll
    for (int i = 0; i < 2; i++)
#pragma unroll
        for (int j = 0; j < 4; j++) acc[i][j] = (f32x4){0.f, 0.f, 0.f, 0.f};

    const int arow = tid >> 2;
    const int acb  = (tid & 3) * 8;

    auto stageA = [&](int buf, int k0) {
        const size_t base = (size_t)(bm + arow) * 512 + k0 + acb;
        const bf16x8 a0 = *(const bf16x8*)(Opart + base);
        const bf16x8 a1 = *(const bf16x8*)(Opart + PO + base);
        const bf16x8 a2 = *(const bf16x8*)(Opart + 2 * PO + base);
        const float rv = Lr[arow * 16 + (k0 >> 5)];
        bf16x8 o;
#pragma unroll
        for (int e = 0; e < 8; e++)
            o[e] = f2bf((bf2f(a0[e]) + bf2f(a1[e]) + bf2f(a2[e])) * rv);
        *(bf16x8*)&As[buf][arow * 32 + acb] = o;
    };
    auto stageB = [&](int buf, int k0) {
        const short* Bb = Bw + (size_t)bn * 512 + k0;
#pragma unroll
        for (int j = 0; j < 2; j++) {
            const int idx = j * 256 + wave * 64 + lane;
            gld_lds16(Bb + (size_t)(idx >> 2) * 512 + (idx & 3) * 8,
                      &Bs[buf][(size_t)(j * 256 + wave * 64) * 8]);
        }
    };
    auto compute = [&](int buf) {
        bf16x8 af[2], bfr[4];
#pragma unroll
        for (int i = 0; i < 2; i++)
            af[i] = *(const bf16x8*)&As[buf][(wr + i * 16 + l16) * 32 + quad * 8];
#pragma unroll
        for (int j = 0; j < 4; j++)
            bfr[j] = *(const bf16x8*)&Bs[buf][(wc + j * 16 + l16) * 32 + quad * 8];
#pragma unroll
        for (int i = 0; i < 2; i++)
#pragma unroll
            for (int j = 0; j < 4; j++)
                acc[i][j] = __builtin_amdgcn_mfma_f32_16x16x32_bf16(af[i], bfr[j], acc[i][j], 0, 0, 0);
    };

    stageB(0, 0);
    stageA(0, 0);
    __syncthreads();
    int cur = 0;
    for (int k0 = 32; k0 < 512; k0 += 32) {
        stageB(cur ^ 1, k0);
        stageA(cur ^ 1, k0);
        compute(cur);
        __syncthreads();
        cur ^= 1;
    }
    compute(cur);

#pragma unroll
    for (int i = 0; i < 2; i++) {
#pragma unroll
        for (int r = 0; r < 4; r++) {
            const int row = bm + wr + i * 16 + quad * 4 + r;
#pragma unroll
            for (int j = 0; j < 4; j++) {
                const int col = bn + wc + j * 16 + l16;
                float v = acc[i][j][r] + bias[col] + bf2f(resb[(size_t)row * 512 + col]);
                Cout[(size_t)row * 512 + col] = v;
            }
        }
    }
}

// ---------------- MFMA flash attention, 3-way split-K, NN-table bias --------
// BARRIER-FREE K-loop: each wave stages and consumes only ITS two heads' K/V.
__global__ __launch_bounds__(512) void attn_mfma(
    const short* __restrict__ qkv,
    const int* __restrict__ dist,
    const float* __restrict__ dist3d,
    const float* __restrict__ demb,
    const short* __restrict__ Tg,
    short* __restrict__ O_part,        // [3][4096][512] bf16 unnormalized
    float* __restrict__ l_part)        // [3][4096][16]  fp32
{
    const int blk  = blockIdx.x;
    const int b    = blk & 7;
    const int t3   = blk >> 3;
    const int part = t3 % 3;
    const int q0   = (t3 / 3) * 16;
    const int tid  = threadIdx.x;
    const int wave = tid >> 6;
    const int lane = tid & 63;
    const int l16  = lane & 15;
    const int quad = lane >> 4;

    __shared__ short Kc[NH * 16 * 32];
    __shared__ short Vc[NH * 16 * 32];
    __shared__ short Pb[8 * 16 * 32];
    __shared__ short Tt[194 * 18];   // rbf NN table, stride-18 pad
    __shared__ short Db[128 * 18];   // dist_emb, stride-18 pad

    for (int i = tid; i < 8 * 16 * 32; i += 512) Pb[i] = 0;
    for (int i = tid; i < 194 * 16; i += 512) Tt[(i >> 4) * 18 + (i & 15)] = Tg[i];
    for (int i = tid; i < 128 * 16; i += 512) Db[(i >> 4) * 18 + (i & 15)] = f2bf(demb[i]);

    const float scale = 0.17677669529663687f;
    bf16x8 qf[2];
#pragma unroll
    for (int h = 0; h < 2; h++) {
        const int hh = wave * 2 + h;
        qf[h] = *(const bf16x8*)(qkv + (size_t)(b * NN + q0 + l16) * TD + hh * DH + quad * 8);
    }

    f32x4 O[2][2];
    float lsum[2][4];
#pragma unroll
    for (int h = 0; h < 2; h++) {
#pragma unroll
        for (int tt = 0; tt < 2; tt++) O[h][tt] = (f32x4){0.f, 0.f, 0.f, 0.f};
#pragma unroll
        for (int r = 0; r < 4; r++) lsum[h][r] = 0.f;
    }

    __syncthreads();  // tables + Pb zero visible; last barrier.

    const int cbeg = part * 11;
    const int cend = (part == 2) ? 32 : cbeg + 11;

    const int sk = lane >> 2;
    const int sc = lane & 3;

    for (int c = cbeg; c < cend; c++) {
        const int k0 = c * 16;
        const size_t rowb = (size_t)(b * NN + k0 + sk) * TD + sc * 8;
#pragma unroll
        for (int h = 0; h < 2; h++) {
            const int hh = wave * 2 + h;
            gld_lds16(qkv + rowb + DD + hh * DH,     &Kc[hh * 512]);
            gld_lds16(qkv + rowb + 2 * DD + hh * DH, &Vc[hh * 512]);
        }
        // ---- bias: dist_emb gather + nearest-neighbor rbf table ----
        float biasr[2][4];
        {
            const int hh0 = wave * 2, hh1 = hh0 + 1;
#pragma unroll
            for (int r = 0; r < 4; r++) {
                const size_t off = ((size_t)(b * NN) + q0 + quad * 4 + r) * NN + k0 + l16;
                int dc = dist[off];
                dc = min(max(dc, 0), MAXD - 1);
                int ii = (int)(dist3d[off] * 9.6f + 0.5f);  // 192/20
                ii = min(ii, 192);
                biasr[0][r] = bf2f(Db[dc * 18 + hh0]) + bf2f(Tt[ii * 18 + hh0]);
                biasr[1][r] = bf2f(Db[dc * 18 + hh1]) + bf2f(Tt[ii * 18 + hh1]);
            }
        }
        asm volatile("" ::: "memory");
        __builtin_amdgcn_s_waitcnt(0x0F70);  // vmcnt(0)
        asm volatile("" ::: "memory");
#pragma unroll
        for (int h = 0; h < 2; h++) {
            const int hh = wave * 2 + h;
            const bf16x8 kf = *(const bf16x8*)&Kc[hh * 512 + l16 * 32 + quad * 8];
            f32x4 s = __builtin_amdgcn_mfma_f32_16x16x32_bf16(
                qf[h], kf, (f32x4){0.f, 0.f, 0.f, 0.f}, 0, 0, 0);
            float pv[4];
#pragma unroll
            for (int r = 0; r < 4; r++) {
                float sv = s[r] * scale + biasr[h][r];
                sv = fminf(sv, 20.f);
                pv[r] = __expf(sv);
                lsum[h][r] += pv[r];
                Pb[wave * 512 + (quad * 4 + r) * 32 + l16] = f2bf(pv[r]);
            }
            const bf16x8 pf = *(const bf16x8*)&Pb[wave * 512 + l16 * 32 + quad * 8];
#pragma unroll
            for (int tt = 0; tt < 2; tt++) {
                bf16x8 vf;
                if (quad < 2) {
#pragma unroll
                    for (int j = 0; j < 8; j++)
                        vf[j] = Vc[hh * 512 + (quad * 8 + j) * 32 + tt * 16 + l16];
                } else {
#pragma unroll
                    for (int j = 0; j < 8; j++) vf[j] = 0;
                }
                O[h][tt] = __builtin_amdgcn_mfma_f32_16x16x32_bf16(pf, vf, O[h][tt], 0, 0, 0);
            }
        }
        asm volatile("" ::: "memory");
        __builtin_amdgcn_s_waitcnt(0xC07F);  // lgkmcnt(0)
        asm volatile("" ::: "memory");
    }
    const size_t poff = (size_t)part * 4096;
#pragma unroll
    for (int h = 0; h < 2; h++) {
        const int hh = wave * 2 + h;
#pragma unroll
        for (int m = 1; m < 16; m <<= 1)
#pragma unroll
            for (int r = 0; r < 4; r++) lsum[h][r] += __shfl_xor(lsum[h][r], m);
#pragma unroll
        for (int r = 0; r < 4; r++) {
            const size_t row = (size_t)(b * NN + q0 + quad * 4 + r);
#pragma unroll
            for (int tt = 0; tt < 2; tt++)
                O_part[(poff + row) * DD + hh * DH + tt * 16 + l16] = f2bf(O[h][tt][r]);
            if (l16 == 0) l_part[(poff + row) * NH + hh] = lsum[h][r];
        }
    }
}

extern "C" void kernel_launch(void* const* d_in, const int* in_sizes, int n_in,
                              void* d_out, int out_size, void* d_ws, size_t ws_size,
                              hipStream_t stream) {
    const float* x      = (const float*)d_in[0];
    const int*   dist   = (const int*)d_in[1];
    const float* dist3d = (const float*)d_in[2];
    const float* n1g    = (const float*)d_in[3];
    const float* n1b    = (const float*)d_in[4];
    const float* win    = (const float*)d_in[5];
    const float* bin    = (const float*)d_in[6];
    const float* wo     = (const float*)d_in[7];
    const float* bo     = (const float*)d_in[8];
    const float* demb   = (const float*)d_in[9];
    const float* rbfw   = (const float*)d_in[10];
    const float* rbfb   = (const float*)d_in[11];
    const float* n2g    = (const float*)d_in[12];
    const float* n2b    = (const float*)d_in[13];
    const float* w1     = (const float*)d_in[14];
    const float* b1     = (const float*)d_in[15];
    const float* w2     = (const float*)d_in[16];
    const float* b2     = (const float*)d_in[17];

    // workspace. Opart region (16 MB) is reused by mid_bf (ffn1 output) since
    // O_part+l_part are dead after gemm_op, which runs before ffn1.
    char* p = (char*)d_ws;
    short* h_bf   = (short*)p; p += (size_t)4096 * 512 * 2;
    short* qkv_bf = (short*)p; p += (size_t)4096 * 1536 * 2;
    float* hres   = (float*)p; p += (size_t)4096 * 512 * 4;
    short* h2_bf  = (short*)p; p += (size_t)4096 * 512 * 2;
    short* win_bf = (short*)p; p += (size_t)1536 * 512 * 2;
    short* wo_bf  = (short*)p; p += (size_t)512 * 512 * 2;
    short* w1_bf  = (short*)p; p += (size_t)2048 * 512 * 2;
    short* w2_bf  = (short*)p; p += (size_t)512 * 2048 * 2;
    short* Tg     = (short*)p; p += (size_t)8192;  // 194*16 bf16 = 6208 B
    short* O_part = (short*)p;
    short* mid_bf = (short*)p;  // overlays O_part region
    p += (size_t)4096 * 2048 * 2;
    float* l_part = (float*)p; p += (size_t)3 * 4096 * 16 * 4;

    const int M = BB * NN;  // 4096

    cvt_weights<<<dim3(1024, 5), 256, 0, stream>>>(
        win, wo, w1, w2, win_bf, wo_bf, w1_bf, w2_bf, rbfw, rbfb, Tg,
        1536 * 512, 512 * 512, 2048 * 512, 512 * 2048);
    ln_kernel<<<M, 256, 0, stream>>>(x, n1g, n1b, h_bf);
    gemm_bf16<64, false, false, true><<<dim3(12, 64), 256, 0, stream>>>(
        h_bf, win_bf, bin, nullptr, qkv_bf, M, TD, DD);
    attn_mfma<<<768, 512, 0, stream>>>(
        qkv_bf, dist, dist3d, demb, Tg, O_part, l_part);
    gemm_op<<<dim3(4, 64), 256, 0, stream>>>(
        O_part, l_part, wo_bf, bo, h_bf, hres);
    ln_kernel<<<M, 256, 0, stream>>>(hres, n2g, n2b, h2_bf);
    gemm_bf16<64, true, false, true><<<dim3(16, 64), 256, 0, stream>>>(
        h2_bf, w1_bf, b1, nullptr, mid_bf, M, 2048, DD);
    gemm_bf16<64, false, true, false><<<dim3(4, 64), 256, 0, stream>>>(
        mid_bf, w2_bf, b2, hres, (float*)d_out, M, DD, 2048);
}